// Round 10
// baseline (88.683 us; speedup 1.0000x reference)
//
#include <hip/hip_runtime.h>
#include <math.h>
#include <stdint.h>

#define T_SEQ 2048
#define BATCH 4
#define DMODEL 128
#define DFF 512
#define NHEAD 8
#define EHEAD 16

#define QSCALE (0.022097086912079608f * 1.4426950408889634f)   // rsqrt(T) * log2(e)

typedef __attribute__((ext_vector_type(8))) short bf16x8;
typedef __attribute__((ext_vector_type(4))) short bf16x4;
typedef __attribute__((ext_vector_type(4))) float f32x4;

__device__ __forceinline__ short f2bf(float f) {            // RNE
    uint32_t u = __float_as_uint(f);
    u = u + 0x7FFF + ((u >> 16) & 1);
    return (short)(u >> 16);
}
__device__ __forceinline__ short bftrunc(float f) {         // truncate (cheap)
    return (short)(__float_as_uint(f) >> 16);
}
__device__ __forceinline__ float bf2f(short s) {
    return __uint_as_float(((uint32_t)(unsigned short)s) << 16);
}
__device__ __forceinline__ float exp2_fast(float x) {       // raw v_exp_f32
#if __has_builtin(__builtin_amdgcn_exp2f)
    return __builtin_amdgcn_exp2f(x);
#else
    float r; asm("v_exp_f32 %0, %1" : "=v"(r) : "v"(x)); return r;
#endif
}

#define MFMA16(A, B, C) __builtin_amdgcn_mfma_f32_16x16x32_bf16(A, B, C, 0, 0, 0)

__device__ __forceinline__ void gload16(const void* g, void* l) {
    __builtin_amdgcn_global_load_lds(
        (const __attribute__((address_space(1))) void*)g,
        (__attribute__((address_space(3))) void*)l, 16, 0, 0);
}

// ---------------------------------------------------------------------------
// K0: xpe = x + PE (PE computed once per (t, f-pair), broadcast over batch);
// transpose+convert all weights to bf16.
// ---------------------------------------------------------------------------
__global__ __launch_bounds__(256) void k_pre(const float* __restrict__ x,
                                             const float* __restrict__ WQ,
                                             const float* __restrict__ WK,
                                             const float* __restrict__ WV,
                                             const float* __restrict__ W1,
                                             const float* __restrict__ W2,
                                             float* __restrict__ xpe,
                                             short* __restrict__ xpe16,
                                             short* __restrict__ Wqkvt,
                                             short* __restrict__ W1t,
                                             short* __restrict__ W2t) {
    int bid = blockIdx.x;
    int tid = threadIdx.x;
    if (bid < 512) {                        // PE over T*(D/2) = 131072 pairs
        int idx = bid * 256 + tid;
        int t = idx >> 6, fp = idx & 63;
        float dv = __expf(-(float)(2 * fp) * (9.210340371976184f / 128.0f));
        float ang = (float)t * dv;
        float sn = __sinf(ang), cs = __cosf(ang);
#pragma unroll
        for (int b = 0; b < 4; ++b) {
            size_t base = ((size_t)b * T_SEQ + t) * 128 + 2 * fp;
            float2 xv = *(const float2*)(x + base);
            float v0 = xv.x + sn, v1 = xv.y + cs;
            *(float2*)(xpe + base) = make_float2(v0, v1);
            uint32_t pk = (uint32_t)(unsigned short)f2bf(v0) |
                          ((uint32_t)(unsigned short)f2bf(v1) << 16);
            *(uint32_t*)(xpe16 + base) = pk;
        }
    } else if (bid < 704) {                 // WQ/WK/WV -> [n][k] bf16
        int m = (bid - 512) >> 6;
        int o = ((bid - 512) & 63) * 256 + tid;       // 0..16383
        int n = o >> 7, k = o & 127;
        const float* W = (m == 0) ? WQ : (m == 1) ? WK : WV;
        Wqkvt[m * 16384 + o] = f2bf(W[k * 128 + n]);
    } else if (bid < 960) {                 // W1 [128][512] -> W1t [512][128]
        int o = (bid - 704) * 256 + tid;    // 0..65535
        int n = o >> 7, k = o & 127;
        W1t[o] = f2bf(W1[k * 512 + n]);
    } else {                                // W2 [512][128] -> W2t [128][512]
        int o = (bid - 960) * 256 + tid;    // 0..65535
        int n = o >> 9, k = o & 511;
        W2t[o] = f2bf(W2[k * 128 + n]);
    }
}

// ---------------------------------------------------------------------------
// K1: QKV projection: bf16 MFMA GEMM, W in registers (Wt[n][k] bf16).
// z=0: Qh[hb][t][16] *= QSCALE; z=1: Kh[hb][t][16]; z=2: Vs[hb][e][T]
// ---------------------------------------------------------------------------
__global__ __launch_bounds__(256) void k_qkv(const short* __restrict__ xpe16,
                                             const short* __restrict__ Wqkvt,
                                             short* __restrict__ Qh,
                                             short* __restrict__ Kh,
                                             short* __restrict__ Vs) {
    int z = blockIdx.y;
    const short* Wt = Wqkvt + z * 16384;
    int wave = threadIdx.x >> 6, lane = threadIdx.x & 63;
    int g = lane >> 4, c = lane & 15;
    int row0 = blockIdx.x * 64 + wave * 16;

    bf16x8 wf[8][4];
#pragma unroll
    for (int nt = 0; nt < 8; ++nt)
#pragma unroll
        for (int kk = 0; kk < 4; ++kk)
            wf[nt][kk] = *(const bf16x8*)(Wt + (nt * 16 + c) * 128 + kk * 32 + 8 * g);

    bf16x8 af[4];
#pragma unroll
    for (int kk = 0; kk < 4; ++kk)
        af[kk] = *(const bf16x8*)(xpe16 + (size_t)(row0 + c) * 128 + kk * 32 + 8 * g);

    f32x4 acc[8];
#pragma unroll
    for (int nt = 0; nt < 8; ++nt) acc[nt] = (f32x4){0.f, 0.f, 0.f, 0.f};
#pragma unroll
    for (int kk = 0; kk < 4; ++kk)
#pragma unroll
        for (int nt = 0; nt < 8; ++nt)
            acc[nt] = MFMA16(af[kk], wf[nt][kk], acc[nt]);

    int b = row0 >> 11;
    int t0 = (row0 & (T_SEQ - 1)) + 4 * g;
    if (z < 2) {
        short* dst = (z == 0) ? Qh : Kh;
        float sc = (z == 0) ? QSCALE : 1.0f;
#pragma unroll
        for (int nt = 0; nt < 8; ++nt) {
            int hb = nt * 4 + b;
#pragma unroll
            for (int r = 0; r < 4; ++r)
                dst[(size_t)(hb * T_SEQ + t0 + r) * 16 + c] = f2bf(acc[nt][r] * sc);
        }
    } else {
#pragma unroll
        for (int nt = 0; nt < 8; ++nt) {
            int hb = nt * 4 + b;
            bf16x4 v;
#pragma unroll
            for (int r = 0; r < 4; ++r) v[r] = f2bf(acc[nt][r]);
            *(bf16x4*)(Vs + (size_t)(hb * 16 + c) * T_SEQ + t0) = v;
        }
    }
}

// ---------------------------------------------------------------------------
// K2: column softmax denominators + V scaling. 512-thr blocks (8 waves).
// Block (kc, hb) owns 128 k-cols; wave w = (strip s=w&3 -> 32 cols, half
// h=w>>2 -> q-slots {4h..4h+3} of each staged 256-q tile). Partial sums
// combined via LDS; block scales Vs columns [kc*128, +128) at the end.
// ---------------------------------------------------------------------------
__global__ __launch_bounds__(512, 4) void k_csum(const short* __restrict__ Qh,
                                                 const short* __restrict__ Kh,
                                                 short* __restrict__ Vs) {
    __shared__ __align__(16) short Qt[2][4096];
    __shared__ float csLds[8][32];
    __shared__ float invl[128];
    const bf16x8 zz = {0, 0, 0, 0, 0, 0, 0, 0};
    const f32x4 z = {0.f, 0.f, 0.f, 0.f};

    int kc = blockIdx.x, hb = blockIdx.y;
    int tid = threadIdx.x;
    int wave = tid >> 6, lane = tid & 63;
    int g = lane >> 4, c = lane & 15;
    int s = wave & 3, h = wave >> 2;
    int kw = kc * 128 + s * 32;
    const size_t hbT = (size_t)hb * T_SEQ;
    const short* Qg = Qh + hbT * 16;

    bf16x8 kfA = zz, kfB = zz;
    if (g < 2) {
        kfA = *(const bf16x8*)(Kh + (hbT + kw + c) * 16 + 8 * g);
        kfB = *(const bf16x8*)(Kh + (hbT + kw + 16 + c) * 16 + 8 * g);
    }

    int tstart = kc >> 1;                   // first 256-q tile with q >= kc*128
    gload16(Qg + (size_t)tstart * 4096 + tid * 8, &Qt[0][tid * 8]);
    __syncthreads();

    float csA = 0.f, csB = 0.f;
    for (int t = tstart; t < 8; ++t) {
        int buf = (t - tstart) & 1;
        if (t + 1 < 8)
            gload16(Qg + (size_t)(t + 1) * 4096 + tid * 8, &Qt[buf ^ 1][tid * 8]);
        const short* Qtb = &Qt[buf][0];
#pragma unroll
        for (int sj = 0; sj < 4; ++sj) {
            int ss = 4 * h + sj;
            int q32 = t * 256 + ss * 32;
            if (q32 + 31 < kw) continue;            // fully above diagonal
            bf16x8 qfa = zz, qfb = zz;
            if (g < 2) {
                qfa = *(const bf16x8*)(Qtb + (ss * 32 + c) * 16 + g * 8);
                qfb = *(const bf16x8*)(Qtb + (ss * 32 + 16 + c) * 16 + g * 8);
            }
            f32x4 sA1 = MFMA16(qfa, kfA, z);
            f32x4 sB1 = MFMA16(qfa, kfB, z);
            f32x4 sA2 = MFMA16(qfb, kfA, z);
            f32x4 sB2 = MFMA16(qfb, kfB, z);
            if (q32 >= kw + 32) {                   // fully below diagonal
#pragma unroll
                for (int r = 0; r < 4; ++r) {
                    csA += exp2_fast(sA1[r]) + exp2_fast(sA2[r]);
                    csB += exp2_fast(sB1[r]) + exp2_fast(sB2[r]);
                }
            } else {                                // diagonal region: mask
                int kA = kw + c, kB = kw + 16 + c;
#pragma unroll
                for (int r = 0; r < 4; ++r) {
                    int qa = q32 + 4 * g + r, qb = q32 + 16 + 4 * g + r;
                    csA += (qa >= kA) ? exp2_fast(sA1[r]) : 0.f;
                    csA += (qb >= kA) ? exp2_fast(sA2[r]) : 0.f;
                    csB += (qa >= kB) ? exp2_fast(sB1[r]) : 0.f;
                    csB += (qb >= kB) ? exp2_fast(sB2[r]) : 0.f;
                }
            }
        }
        __syncthreads();
    }

    csA += __shfl_xor(csA, 16);
    csA += __shfl_xor(csA, 32);
    csB += __shfl_xor(csB, 16);
    csB += __shfl_xor(csB, 32);
    if (lane < 32) csLds[wave][lane] = (lane < 16) ? csA : csB;
    __syncthreads();
    if (tid < 128) {                        // strip = tid>>5, col-in-strip = tid&31
        int st = tid >> 5, col = tid & 31;
        invl[st * 32 + col] = 1.0f / (csLds[st][col] + csLds[st + 4][col]);
    }
    __syncthreads();
    if (tid < 256) {                        // scale V cols [kc*128, +128)
        int e = tid >> 4, kcol = (tid & 15) * 8;
        size_t vo = (size_t)(hb * 16 + e) * T_SEQ + kc * 128 + kcol;
        bf16x8 v = *(bf16x8*)(Vs + vo);
        bf16x8 o;
#pragma unroll
        for (int j = 0; j < 8; ++j) o[j] = f2bf(bf2f(v[j]) * invl[kcol + j]);
        *(bf16x8*)(Vs + vo) = o;
    }
}

// ---------------------------------------------------------------------------
// K3: attention output. 512-thr blocks (8 waves). Block (bx, hb): qn = 15-bx
// owns a 128-q chunk; wave w = (strip s=w&3 -> q0w = qn*128+s*32, half h=w>>2
// -> k-slots {4h..4h+3} of each staged 256-k tile). K linear + V e-major
// XOR-swizzled tiles double-buffered via global_load_lds. Partial O combined
// via LDS. O[q] = sum_{k<=q} exp2(S') * Vs (V pre-scaled by 1/colsum).
// ---------------------------------------------------------------------------
__global__ __launch_bounds__(512, 4) void k_attn(const short* __restrict__ Qh,
                                                 const short* __restrict__ Kh,
                                                 const short* __restrict__ Vs,
                                                 short* __restrict__ AObf) {
    __shared__ __align__(16) short Kt[2][4096];
    __shared__ __align__(16) short Vt[2][4096];
    const bf16x8 zz = {0, 0, 0, 0, 0, 0, 0, 0};
    const f32x4 z = {0.f, 0.f, 0.f, 0.f};

    int hb = blockIdx.y, h2 = hb >> 2, b = hb & 3;
    int qn = 15 - (int)blockIdx.x;          // 128-q chunk, longest first
    int tid = threadIdx.x;
    int wave = tid >> 6, lane = tid & 63;
    int g = lane >> 4, c = lane & 15;
    int s = wave & 3, h = wave >> 2;
    int q0w = qn * 128 + s * 32;
    const size_t hbT = (size_t)hb * T_SEQ;
    const short* Kg = Kh + hbT * 16;
    const short* Vg = Vs + (size_t)hb * 16 * T_SEQ;

    bf16x8 qf0 = zz, qf1 = zz;
    if (g < 2) {
        qf0 = *(const bf16x8*)(Qh + (hbT + q0w + c) * 16 + 8 * g);
        qf1 = *(const bf16x8*)(Qh + (hbT + q0w + 16 + c) * 16 + 8 * g);
    }

    int nT = (qn >> 1) + 1;                 // 256-k tiles this block touches

    // K: 512 thr x 16B = 8 KB linear. V: granule gi=tid: e=tid>>5, slot
    // jp=tid&31 <- global granule j = jp ^ (e&7) (XOR within 8-granule group).
#define STAGE(bf, kt)                                                        \
    do {                                                                     \
        int k0s = (kt) * 256;                                                \
        gload16(Kg + (size_t)k0s * 16 + tid * 8, &Kt[bf][tid * 8]);          \
        int e0 = tid >> 5, jp = tid & 31, j0 = jp ^ (e0 & 7);                \
        gload16(Vg + (size_t)e0 * T_SEQ + k0s + j0 * 8, &Vt[bf][tid * 8]);   \
    } while (0)

    STAGE(0, 0);
    __syncthreads();

    f32x4 acc0 = z, acc1 = z;
    for (int t = 0; t < nT; ++t) {
        int buf = t & 1;
        if (t + 1 < nT) STAGE(buf ^ 1, t + 1);
        const short* Ktb = &Kt[buf][0];
        const short* Vtb = &Vt[buf][0];
#pragma unroll
        for (int sj = 0; sj < 4; ++sj) {
            int ss = 4 * h + sj;
            int k32 = t * 256 + ss * 32;
            if (k32 > q0w + 31) continue;           // above causal range
            bf16x8 kf0 = zz, kf1 = zz;
            if (g < 2) {
                kf0 = *(const bf16x8*)(Ktb + (ss * 32 + c) * 16 + g * 8);
                kf1 = *(const bf16x8*)(Ktb + (ss * 32 + 16 + c) * 16 + g * 8);
            }
            int ja = ss * 4 + (g >> 1);             // granule in 32-granule row
            const short* vrow = Vtb + c * 256 + ((g & 1) << 2);
            bf16x4 v0 = *(const bf16x4*)(vrow + ((ja ^ (c & 7)) << 3));
            bf16x4 v1 = *(const bf16x4*)(vrow + (((ja + 2) ^ (c & 7)) << 3));
            f32x4 s0 = MFMA16(kf0, qf0, z);
            f32x4 s1 = MFMA16(kf1, qf0, z);
            f32x4 s2 = MFMA16(kf0, qf1, z);
            f32x4 s3 = MFMA16(kf1, qf1, z);
            bf16x8 aA, aB, vf;
            if (k32 + 31 <= q0w) {                  // full pair, no masking
#pragma unroll
                for (int r = 0; r < 4; ++r) {
                    aA[r] = bftrunc(exp2_fast(s0[r]));
                    aA[4 + r] = bftrunc(exp2_fast(s1[r]));
                    aB[r] = bftrunc(exp2_fast(s2[r]));
                    aB[4 + r] = bftrunc(exp2_fast(s3[r]));
                    vf[r] = v0[r];
                    vf[4 + r] = v1[r];
                }
            } else {                                // causal boundary: mask
                int qa = q0w + c, qb = q0w + 16 + c;
                int ka = k32 + 4 * g, kb = k32 + 16 + 4 * g;
#pragma unroll
                for (int r = 0; r < 4; ++r) {
                    aA[r] = (ka + r <= qa) ? bftrunc(exp2_fast(s0[r])) : (short)0;
                    aA[4 + r] = (kb + r <= qa) ? bftrunc(exp2_fast(s1[r])) : (short)0;
                    aB[r] = (ka + r <= qb) ? bftrunc(exp2_fast(s2[r])) : (short)0;
                    aB[4 + r] = (kb + r <= qb) ? bftrunc(exp2_fast(s3[r])) : (short)0;
                    vf[r] = v0[r];
                    vf[4 + r] = v1[r];
                }
            }
            acc0 = MFMA16(aA, vf, acc0);
            acc1 = MFMA16(aB, vf, acc1);
        }
        __syncthreads();
    }
#undef STAGE

    // combine halves: h=1 waves dump partials to LDS, h=0 waves add and store.
    float* Of = (float*)&Kt[0][0];          // 8 KB, staging done
    if (h == 1) {
#pragma unroll
        for (int r = 0; r < 4; ++r) {
            Of[r * 256 + s * 64 + lane] = acc0[r];
            Of[(4 + r) * 256 + s * 64 + lane] = acc1[r];
        }
    }
    __syncthreads();
    if (h == 0) {
#pragma unroll
        for (int r = 0; r < 4; ++r) {
            acc0[r] += Of[r * 256 + s * 64 + lane];
            acc1[r] += Of[(4 + r) * 256 + s * 64 + lane];
        }
#pragma unroll
        for (int r = 0; r < 4; ++r) {
            AObf[(size_t)(b * T_SEQ + q0w + 4 * g + r) * DMODEL + h2 * EHEAD + c] = f2bf(acc0[r]);
            AObf[(size_t)(b * T_SEQ + q0w + 16 + 4 * g + r) * DMODEL + h2 * EHEAD + c] = f2bf(acc1[r]);
        }
    }
}

// ---------------------------------------------------------------------------
// K4: ff1 = relu(AO @ W1 + b1) -> F bf16 [8192][512]. W1t[n][k] in registers.
// ---------------------------------------------------------------------------
__global__ __launch_bounds__(256) void k_ff1(const short* __restrict__ AObf,
                                             const short* __restrict__ W1t,
                                             const float* __restrict__ b1,
                                             short* __restrict__ F) {
    int nc = blockIdx.y;
    int wave = threadIdx.x >> 6, lane = threadIdx.x & 63;
    int g = lane >> 4, c = lane & 15;
    int row0 = blockIdx.x * 64 + wave * 16;

    bf16x8 wf[8][4];
#pragma unroll
    for (int nt = 0; nt < 8; ++nt)
#pragma unroll
        for (int kk = 0; kk < 4; ++kk)
            wf[nt][kk] = *(const bf16x8*)(W1t + (nc * 128 + nt * 16 + c) * 128 + kk * 32 + 8 * g);

    bf16x8 af[4];
#pragma unroll
    for (int kk = 0; kk < 4; ++kk)
        af[kk] = *(const bf16x8*)(AObf + (size_t)(row0 + c) * 128 + kk * 32 + 8 * g);

    f32x4 acc[8];
#pragma unroll
    for (int nt = 0; nt < 8; ++nt) acc[nt] = (f32x4){0.f, 0.f, 0.f, 0.f};
#pragma unroll
    for (int kk = 0; kk < 4; ++kk)
#pragma unroll
        for (int nt = 0; nt < 8; ++nt)
            acc[nt] = MFMA16(af[kk], wf[nt][kk], acc[nt]);

#pragma unroll
    for (int nt = 0; nt < 8; ++nt) {
        int col = nc * 128 + nt * 16 + c;
        float bb = b1[col];
#pragma unroll
        for (int r = 0; r < 4; ++r)
            F[(size_t)(row0 + 4 * g + r) * DFF + col] = f2bf(fmaxf(acc[nt][r] + bb, 0.f));
    }
}

// ---------------------------------------------------------------------------
// K5: out = F @ W2 + b2 + xpe. W2t[n][k=512] in registers (32-col groups).
// ---------------------------------------------------------------------------
__global__ __launch_bounds__(256) void k_ff2(const short* __restrict__ F,
                                             const short* __restrict__ W2t,
                                             const float* __restrict__ b2,
                                             const float* __restrict__ xpe,
                                             float* __restrict__ out) {
    int ng = blockIdx.y;
    int wave = threadIdx.x >> 6, lane = threadIdx.x & 63;
    int g = lane >> 4, c = lane & 15;
    int row0 = blockIdx.x * 64 + wave * 16;

    bf16x8 wf[2][16];
#pragma unroll
    for (int nt = 0; nt < 2; ++nt)
#pragma unroll
        for (int kk = 0; kk < 16; ++kk)
            wf[nt][kk] = *(const bf16x8*)(W2t + (ng * 32 + nt * 16 + c) * 512 + kk * 32 + 8 * g);

    f32x4 acc[2];
    acc[0] = (f32x4){0.f, 0.f, 0.f, 0.f};
    acc[1] = (f32x4){0.f, 0.f, 0.f, 0.f};
#pragma unroll
    for (int kk = 0; kk < 16; ++kk) {
        bf16x8 a = *(const bf16x8*)(F + (size_t)(row0 + c) * 512 + kk * 32 + 8 * g);
        acc[0] = MFMA16(a, wf[0][kk], acc[0]);
        acc[1] = MFMA16(a, wf[1][kk], acc[1]);
    }
#pragma unroll
    for (int nt = 0; nt < 2; ++nt) {
        int col = ng * 32 + nt * 16 + c;
        float bb = b2[col];
#pragma unroll
        for (int r = 0; r < 4; ++r) {
            size_t o = (size_t)(row0 + 4 * g + r) * DMODEL + col;
            out[o] = acc[nt][r] + bb + xpe[o];
        }
    }
}

// ---------------------------------------------------------------------------
extern "C" void kernel_launch(void* const* d_in, const int* in_sizes, int n_in,
                              void* d_out, int out_size, void* d_ws, size_t ws_size,
                              hipStream_t stream) {
    const float* x  = (const float*)d_in[0];
    const float* WQ = (const float*)d_in[1];
    const float* WK = (const float*)d_in[2];
    const float* WV = (const float*)d_in[3];
    const float* W1 = (const float*)d_in[4];
    const float* b1 = (const float*)d_in[5];
    const float* W2 = (const float*)d_in[6];
    const float* b2 = (const float*)d_in[7];
    float* out = (float*)d_out;

    const size_t NTD = (size_t)BATCH * T_SEQ * DMODEL;   // 1048576
    float* xpe   = (float*)d_ws;
    short* xpe16 = (short*)(xpe + NTD);
    short* Qh    = xpe16 + NTD;
    short* Kh    = Qh + NTD;
    short* Vs    = Kh + NTD;
    short* AObf  = Vs + NTD;
    short* F     = AObf + NTD;                           // 8192*512 shorts
    short* Wqkvt = F + 4 * NTD;
    short* W1t   = Wqkvt + 3 * 16384;
    short* W2t   = W1t + 65536;

    k_pre<<<dim3(1216), dim3(256), 0, stream>>>(x, WQ, WK, WV, W1, W2,
                                                xpe, xpe16, Wqkvt, W1t, W2t);

    k_qkv<<<dim3(128, 3), dim3(256), 0, stream>>>(xpe16, Wqkvt, Qh, Kh, Vs);

    k_csum<<<dim3(16, 32), dim3(512), 0, stream>>>(Qh, Kh, Vs);

    k_attn<<<dim3(16, 32), dim3(512), 0, stream>>>(Qh, Kh, Vs, AObf);

    k_ff1<<<dim3(128, 4), dim3(256), 0, stream>>>(AObf, W1t, b1, F);

    k_ff2<<<dim3(128, 4), dim3(256), 0, stream>>>(F, W2t, b2, xpe, out);
}

// Round 11
// 83.872 us; speedup vs baseline: 1.0574x; 1.0574x over previous
//
#include <hip/hip_runtime.h>
#include <math.h>
#include <stdint.h>

#define T_SEQ 2048
#define BATCH 4
#define DMODEL 128
#define DFF 512
#define NHEAD 8
#define EHEAD 16

#define QSCALE (0.022097086912079608f * 1.4426950408889634f)   // rsqrt(T) * log2(e)

typedef __attribute__((ext_vector_type(8))) short bf16x8;
typedef __attribute__((ext_vector_type(4))) short bf16x4;
typedef __attribute__((ext_vector_type(4))) float f32x4;

__device__ __forceinline__ short f2bf(float f) {            // RNE
    uint32_t u = __float_as_uint(f);
    u = u + 0x7FFF + ((u >> 16) & 1);
    return (short)(u >> 16);
}
__device__ __forceinline__ short bftrunc(float f) {         // truncate (cheap)
    return (short)(__float_as_uint(f) >> 16);
}
__device__ __forceinline__ float bf2f(short s) {
    return __uint_as_float(((uint32_t)(unsigned short)s) << 16);
}
__device__ __forceinline__ float exp2_fast(float x) {       // raw v_exp_f32
#if __has_builtin(__builtin_amdgcn_exp2f)
    return __builtin_amdgcn_exp2f(x);
#else
    float r; asm("v_exp_f32 %0, %1" : "=v"(r) : "v"(x)); return r;
#endif
}

#define MFMA16(A, B, C) __builtin_amdgcn_mfma_f32_16x16x32_bf16(A, B, C, 0, 0, 0)

__device__ __forceinline__ void gload16(const void* g, void* l) {
    __builtin_amdgcn_global_load_lds(
        (const __attribute__((address_space(1))) void*)g,
        (__attribute__((address_space(3))) void*)l, 16, 0, 0);
}

// ---------------------------------------------------------------------------
// K0: xpe = x + PE (PE computed once per (t, f-pair), broadcast over batch);
// transpose+convert all weights to bf16.
// ---------------------------------------------------------------------------
__global__ __launch_bounds__(256) void k_pre(const float* __restrict__ x,
                                             const float* __restrict__ WQ,
                                             const float* __restrict__ WK,
                                             const float* __restrict__ WV,
                                             const float* __restrict__ W1,
                                             const float* __restrict__ W2,
                                             float* __restrict__ xpe,
                                             short* __restrict__ xpe16,
                                             short* __restrict__ Wqkvt,
                                             short* __restrict__ W1t,
                                             short* __restrict__ W2t) {
    int bid = blockIdx.x;
    int tid = threadIdx.x;
    if (bid < 512) {                        // PE over T*(D/2) = 131072 pairs
        int idx = bid * 256 + tid;
        int t = idx >> 6, fp = idx & 63;
        float dv = __expf(-(float)(2 * fp) * (9.210340371976184f / 128.0f));
        float ang = (float)t * dv;
        float sn = __sinf(ang), cs = __cosf(ang);
#pragma unroll
        for (int b = 0; b < 4; ++b) {
            size_t base = ((size_t)b * T_SEQ + t) * 128 + 2 * fp;
            float2 xv = *(const float2*)(x + base);
            float v0 = xv.x + sn, v1 = xv.y + cs;
            *(float2*)(xpe + base) = make_float2(v0, v1);
            uint32_t pk = (uint32_t)(unsigned short)f2bf(v0) |
                          ((uint32_t)(unsigned short)f2bf(v1) << 16);
            *(uint32_t*)(xpe16 + base) = pk;
        }
    } else if (bid < 704) {                 // WQ/WK/WV -> [n][k] bf16
        int m = (bid - 512) >> 6;
        int o = ((bid - 512) & 63) * 256 + tid;       // 0..16383
        int n = o >> 7, k = o & 127;
        const float* W = (m == 0) ? WQ : (m == 1) ? WK : WV;
        Wqkvt[m * 16384 + o] = f2bf(W[k * 128 + n]);
    } else if (bid < 960) {                 // W1 [128][512] -> W1t [512][128]
        int o = (bid - 704) * 256 + tid;    // 0..65535
        int n = o >> 7, k = o & 127;
        W1t[o] = f2bf(W1[k * 512 + n]);
    } else {                                // W2 [512][128] -> W2t [128][512]
        int o = (bid - 960) * 256 + tid;    // 0..65535
        int n = o >> 9, k = o & 511;
        W2t[o] = f2bf(W2[k * 128 + n]);
    }
}

// ---------------------------------------------------------------------------
// K1: QKV projection: bf16 MFMA GEMM, W in registers (Wt[n][k] bf16).
// z=0: Qh[hb][t][16] *= QSCALE; z=1: Kh[hb][t][16]; z=2: Vs[hb][e][T]
// ---------------------------------------------------------------------------
__global__ __launch_bounds__(256) void k_qkv(const short* __restrict__ xpe16,
                                             const short* __restrict__ Wqkvt,
                                             short* __restrict__ Qh,
                                             short* __restrict__ Kh,
                                             short* __restrict__ Vs) {
    int z = blockIdx.y;
    const short* Wt = Wqkvt + z * 16384;
    int wave = threadIdx.x >> 6, lane = threadIdx.x & 63;
    int g = lane >> 4, c = lane & 15;
    int row0 = blockIdx.x * 64 + wave * 16;

    bf16x8 wf[8][4];
#pragma unroll
    for (int nt = 0; nt < 8; ++nt)
#pragma unroll
        for (int kk = 0; kk < 4; ++kk)
            wf[nt][kk] = *(const bf16x8*)(Wt + (nt * 16 + c) * 128 + kk * 32 + 8 * g);

    bf16x8 af[4];
#pragma unroll
    for (int kk = 0; kk < 4; ++kk)
        af[kk] = *(const bf16x8*)(xpe16 + (size_t)(row0 + c) * 128 + kk * 32 + 8 * g);

    f32x4 acc[8];
#pragma unroll
    for (int nt = 0; nt < 8; ++nt) acc[nt] = (f32x4){0.f, 0.f, 0.f, 0.f};
#pragma unroll
    for (int kk = 0; kk < 4; ++kk)
#pragma unroll
        for (int nt = 0; nt < 8; ++nt)
            acc[nt] = MFMA16(af[kk], wf[nt][kk], acc[nt]);

    int b = row0 >> 11;
    int t0 = (row0 & (T_SEQ - 1)) + 4 * g;
    if (z < 2) {
        short* dst = (z == 0) ? Qh : Kh;
        float sc = (z == 0) ? QSCALE : 1.0f;
#pragma unroll
        for (int nt = 0; nt < 8; ++nt) {
            int hb = nt * 4 + b;
#pragma unroll
            for (int r = 0; r < 4; ++r)
                dst[(size_t)(hb * T_SEQ + t0 + r) * 16 + c] = f2bf(acc[nt][r] * sc);
        }
    } else {
#pragma unroll
        for (int nt = 0; nt < 8; ++nt) {
            int hb = nt * 4 + b;
            bf16x4 v;
#pragma unroll
            for (int r = 0; r < 4; ++r) v[r] = f2bf(acc[nt][r]);
            *(bf16x4*)(Vs + (size_t)(hb * 16 + c) * T_SEQ + t0) = v;
        }
    }
}

// ---------------------------------------------------------------------------
// K2: column softmax denominators + V scaling. 512-thr blocks (8 waves).
// Block (kc, hb) owns 128 k-cols; wave w = (strip s=w&3 -> 32 cols, half
// h=w>>2 -> q-slots {4h..4h+3} of each staged 256-q tile). Partial sums
// combined via LDS; block scales Vs columns [kc*128, +128) at the end.
// ---------------------------------------------------------------------------
__global__ __launch_bounds__(512, 4) void k_csum(const short* __restrict__ Qh,
                                                 const short* __restrict__ Kh,
                                                 short* __restrict__ Vs) {
    __shared__ __align__(16) short Qt[2][4096];
    __shared__ float csLds[8][32];
    __shared__ float invl[128];
    const bf16x8 zz = {0, 0, 0, 0, 0, 0, 0, 0};
    const f32x4 z = {0.f, 0.f, 0.f, 0.f};

    int kc = blockIdx.x, hb = blockIdx.y;
    int tid = threadIdx.x;
    int wave = tid >> 6, lane = tid & 63;
    int g = lane >> 4, c = lane & 15;
    int s = wave & 3, h = wave >> 2;
    int kw = kc * 128 + s * 32;
    const size_t hbT = (size_t)hb * T_SEQ;
    const short* Qg = Qh + hbT * 16;

    bf16x8 kfA = zz, kfB = zz;
    if (g < 2) {
        kfA = *(const bf16x8*)(Kh + (hbT + kw + c) * 16 + 8 * g);
        kfB = *(const bf16x8*)(Kh + (hbT + kw + 16 + c) * 16 + 8 * g);
    }

    int tstart = kc >> 1;                   // first 256-q tile with q >= kc*128
    gload16(Qg + (size_t)tstart * 4096 + tid * 8, &Qt[0][tid * 8]);
    __syncthreads();

    float csA = 0.f, csB = 0.f;
    for (int t = tstart; t < 8; ++t) {
        int buf = (t - tstart) & 1;
        if (t + 1 < 8)
            gload16(Qg + (size_t)(t + 1) * 4096 + tid * 8, &Qt[buf ^ 1][tid * 8]);
        const short* Qtb = &Qt[buf][0];
#pragma unroll
        for (int sj = 0; sj < 4; ++sj) {
            int ss = 4 * h + sj;
            int q32 = t * 256 + ss * 32;
            if (q32 + 31 < kw) continue;            // fully above diagonal
            bf16x8 qfa = zz, qfb = zz;
            if (g < 2) {
                qfa = *(const bf16x8*)(Qtb + (ss * 32 + c) * 16 + g * 8);
                qfb = *(const bf16x8*)(Qtb + (ss * 32 + 16 + c) * 16 + g * 8);
            }
            f32x4 sA1 = MFMA16(qfa, kfA, z);
            f32x4 sB1 = MFMA16(qfa, kfB, z);
            f32x4 sA2 = MFMA16(qfb, kfA, z);
            f32x4 sB2 = MFMA16(qfb, kfB, z);
            if (q32 >= kw + 32) {                   // fully below diagonal
#pragma unroll
                for (int r = 0; r < 4; ++r) {
                    csA += exp2_fast(sA1[r]) + exp2_fast(sA2[r]);
                    csB += exp2_fast(sB1[r]) + exp2_fast(sB2[r]);
                }
            } else {                                // diagonal region: mask
                int kA = kw + c, kB = kw + 16 + c;
#pragma unroll
                for (int r = 0; r < 4; ++r) {
                    int qa = q32 + 4 * g + r, qb = q32 + 16 + 4 * g + r;
                    csA += (qa >= kA) ? exp2_fast(sA1[r]) : 0.f;
                    csA += (qb >= kA) ? exp2_fast(sA2[r]) : 0.f;
                    csB += (qa >= kB) ? exp2_fast(sB1[r]) : 0.f;
                    csB += (qb >= kB) ? exp2_fast(sB2[r]) : 0.f;
                }
            }
        }
        __syncthreads();
    }

    csA += __shfl_xor(csA, 16);
    csA += __shfl_xor(csA, 32);
    csB += __shfl_xor(csB, 16);
    csB += __shfl_xor(csB, 32);
    if (lane < 32) csLds[wave][lane] = (lane < 16) ? csA : csB;
    __syncthreads();
    if (tid < 128) {                        // strip = tid>>5, col-in-strip = tid&31
        int st = tid >> 5, col = tid & 31;
        invl[st * 32 + col] = 1.0f / (csLds[st][col] + csLds[st + 4][col]);
    }
    __syncthreads();
    if (tid < 256) {                        // scale V cols [kc*128, +128)
        int e = tid >> 4, kcol = (tid & 15) * 8;
        size_t vo = (size_t)(hb * 16 + e) * T_SEQ + kc * 128 + kcol;
        bf16x8 v = *(bf16x8*)(Vs + vo);
        bf16x8 o;
#pragma unroll
        for (int j = 0; j < 8; ++j) o[j] = f2bf(bf2f(v[j]) * invl[kcol + j]);
        *(bf16x8*)(Vs + vo) = o;
    }
}

// ---------------------------------------------------------------------------
// K3: attention output. 512-thr blocks (8 waves). Block (bx, hb): qn = 15-bx
// owns a 128-q chunk; wave w = (strip s=w&3 -> q0w = qn*128+s*32, half h=w>>2
// -> k-slots {4h..4h+3} of each staged 256-k tile). K linear + V e-major
// XOR-swizzled tiles double-buffered via global_load_lds. Partial O combined
// via LDS. O[q] = sum_{k<=q} exp2(S') * Vs (V pre-scaled by 1/colsum).
// ---------------------------------------------------------------------------
__global__ __launch_bounds__(512, 4) void k_attn(const short* __restrict__ Qh,
                                                 const short* __restrict__ Kh,
                                                 const short* __restrict__ Vs,
                                                 short* __restrict__ AObf) {
    __shared__ __align__(16) short Kt[2][4096];
    __shared__ __align__(16) short Vt[2][4096];
    const bf16x8 zz = {0, 0, 0, 0, 0, 0, 0, 0};
    const f32x4 z = {0.f, 0.f, 0.f, 0.f};

    int hb = blockIdx.y, h2 = hb >> 2, b = hb & 3;
    int qn = 15 - (int)blockIdx.x;          // 128-q chunk, longest first
    int tid = threadIdx.x;
    int wave = tid >> 6, lane = tid & 63;
    int g = lane >> 4, c = lane & 15;
    int s = wave & 3, h = wave >> 2;
    int q0w = qn * 128 + s * 32;
    const size_t hbT = (size_t)hb * T_SEQ;
    const short* Kg = Kh + hbT * 16;
    const short* Vg = Vs + (size_t)hb * 16 * T_SEQ;

    bf16x8 qf0 = zz, qf1 = zz;
    if (g < 2) {
        qf0 = *(const bf16x8*)(Qh + (hbT + q0w + c) * 16 + 8 * g);
        qf1 = *(const bf16x8*)(Qh + (hbT + q0w + 16 + c) * 16 + 8 * g);
    }

    int nT = (qn >> 1) + 1;                 // 256-k tiles this block touches

#define STAGE(bf, kt)                                                        \
    do {                                                                     \
        int k0s = (kt) * 256;                                                \
        gload16(Kg + (size_t)k0s * 16 + tid * 8, &Kt[bf][tid * 8]);          \
        int e0 = tid >> 5, jp = tid & 31, j0 = jp ^ (e0 & 7);                \
        gload16(Vg + (size_t)e0 * T_SEQ + k0s + j0 * 8, &Vt[bf][tid * 8]);   \
    } while (0)

    STAGE(0, 0);
    __syncthreads();

    f32x4 acc0 = z, acc1 = z;
    for (int t = 0; t < nT; ++t) {
        int buf = t & 1;
        if (t + 1 < nT) STAGE(buf ^ 1, t + 1);
        const short* Ktb = &Kt[buf][0];
        const short* Vtb = &Vt[buf][0];
#pragma unroll
        for (int sj = 0; sj < 4; ++sj) {
            int ss = 4 * h + sj;
            int k32 = t * 256 + ss * 32;
            if (k32 > q0w + 31) continue;           // above causal range
            bf16x8 kf0 = zz, kf1 = zz;
            if (g < 2) {
                kf0 = *(const bf16x8*)(Ktb + (ss * 32 + c) * 16 + g * 8);
                kf1 = *(const bf16x8*)(Ktb + (ss * 32 + 16 + c) * 16 + g * 8);
            }
            int ja = ss * 4 + (g >> 1);             // granule in 32-granule row
            const short* vrow = Vtb + c * 256 + ((g & 1) << 2);
            bf16x4 v0 = *(const bf16x4*)(vrow + ((ja ^ (c & 7)) << 3));
            bf16x4 v1 = *(const bf16x4*)(vrow + (((ja + 2) ^ (c & 7)) << 3));
            f32x4 s0 = MFMA16(kf0, qf0, z);
            f32x4 s1 = MFMA16(kf1, qf0, z);
            f32x4 s2 = MFMA16(kf0, qf1, z);
            f32x4 s3 = MFMA16(kf1, qf1, z);
            bf16x8 aA, aB, vf;
            if (k32 + 31 <= q0w) {                  // full pair, no masking
#pragma unroll
                for (int r = 0; r < 4; ++r) {
                    aA[r] = bftrunc(exp2_fast(s0[r]));
                    aA[4 + r] = bftrunc(exp2_fast(s1[r]));
                    aB[r] = bftrunc(exp2_fast(s2[r]));
                    aB[4 + r] = bftrunc(exp2_fast(s3[r]));
                    vf[r] = v0[r];
                    vf[4 + r] = v1[r];
                }
            } else {                                // causal boundary: mask
                int qa = q0w + c, qb = q0w + 16 + c;
                int ka = k32 + 4 * g, kb = k32 + 16 + 4 * g;
#pragma unroll
                for (int r = 0; r < 4; ++r) {
                    aA[r] = (ka + r <= qa) ? bftrunc(exp2_fast(s0[r])) : (short)0;
                    aA[4 + r] = (kb + r <= qa) ? bftrunc(exp2_fast(s1[r])) : (short)0;
                    aB[r] = (ka + r <= qb) ? bftrunc(exp2_fast(s2[r])) : (short)0;
                    aB[4 + r] = (kb + r <= qb) ? bftrunc(exp2_fast(s3[r])) : (short)0;
                    vf[r] = v0[r];
                    vf[4 + r] = v1[r];
                }
            }
            acc0 = MFMA16(aA, vf, acc0);
            acc1 = MFMA16(aB, vf, acc1);
        }
        __syncthreads();
    }
#undef STAGE

    // combine halves: h=1 waves dump partials to LDS, h=0 waves add and store.
    float* Of = (float*)&Kt[0][0];          // 8 KB, staging done
    if (h == 1) {
#pragma unroll
        for (int r = 0; r < 4; ++r) {
            Of[r * 256 + s * 64 + lane] = acc0[r];
            Of[(4 + r) * 256 + s * 64 + lane] = acc1[r];
        }
    }
    __syncthreads();
    if (h == 0) {
#pragma unroll
        for (int r = 0; r < 4; ++r) {
            acc0[r] += Of[r * 256 + s * 64 + lane];
            acc1[r] += Of[(4 + r) * 256 + s * 64 + lane];
        }
#pragma unroll
        for (int r = 0; r < 4; ++r) {
            AObf[(size_t)(b * T_SEQ + q0w + 4 * g + r) * DMODEL + h2 * EHEAD + c] = f2bf(acc0[r]);
            AObf[(size_t)(b * T_SEQ + q0w + 16 + 4 * g + r) * DMODEL + h2 * EHEAD + c] = f2bf(acc1[r]);
        }
    }
}

// ---------------------------------------------------------------------------
// K4: fused FF: out = relu(AO@W1+b1)@W2 + b2 + xpe.
// Block owns 16 rows. Phase 1: wave w computes F cols [w*128,+128) -> LDS
// (16 x 516 padded). Phase 2: wave w computes out cols [w*32,+32) from LDS-F.
// Grid 512 blocks x 256 thr. F never touches global memory.
// ---------------------------------------------------------------------------
__global__ __launch_bounds__(256) void k_ff(const short* __restrict__ AObf,
                                            const short* __restrict__ W1t,
                                            const float* __restrict__ b1,
                                            const short* __restrict__ W2t,
                                            const float* __restrict__ b2,
                                            const float* __restrict__ xpe,
                                            float* __restrict__ out) {
    __shared__ __align__(16) short Fl[16][516];
    int w = threadIdx.x >> 6, lane = threadIdx.x & 63;
    int g = lane >> 4, c = lane & 15;
    int row0 = blockIdx.x * 16;

    // ---- phase 1: F[r][w*128 + n] = relu(AO @ W1 + b1) ----
    bf16x8 af[4];
#pragma unroll
    for (int kk = 0; kk < 4; ++kk)
        af[kk] = *(const bf16x8*)(AObf + (size_t)(row0 + c) * 128 + kk * 32 + 8 * g);

    {
        bf16x8 wf[8][4];
#pragma unroll
        for (int nt = 0; nt < 8; ++nt)
#pragma unroll
            for (int kk = 0; kk < 4; ++kk)
                wf[nt][kk] = *(const bf16x8*)(W1t + (w * 128 + nt * 16 + c) * 128 + kk * 32 + 8 * g);

        f32x4 acc[8];
#pragma unroll
        for (int nt = 0; nt < 8; ++nt) acc[nt] = (f32x4){0.f, 0.f, 0.f, 0.f};
#pragma unroll
        for (int kk = 0; kk < 4; ++kk)
#pragma unroll
            for (int nt = 0; nt < 8; ++nt)
                acc[nt] = MFMA16(af[kk], wf[nt][kk], acc[nt]);

#pragma unroll
        for (int nt = 0; nt < 8; ++nt) {
            int col = w * 128 + nt * 16 + c;
            float bb = b1[col];
#pragma unroll
            for (int r = 0; r < 4; ++r)
                Fl[4 * g + r][col] = f2bf(fmaxf(acc[nt][r] + bb, 0.f));
        }
    }
    __syncthreads();

    // ---- phase 2: out cols [w*32, +32) = F @ W2 + b2 + xpe ----
    bf16x8 wf2[2][16];
#pragma unroll
    for (int nt = 0; nt < 2; ++nt)
#pragma unroll
        for (int kk = 0; kk < 16; ++kk)
            wf2[nt][kk] = *(const bf16x8*)(W2t + (w * 32 + nt * 16 + c) * 512 + kk * 32 + 8 * g);

    f32x4 acc2[2];
    acc2[0] = (f32x4){0.f, 0.f, 0.f, 0.f};
    acc2[1] = (f32x4){0.f, 0.f, 0.f, 0.f};
#pragma unroll
    for (int kk = 0; kk < 16; ++kk) {
        bf16x8 a = *(const bf16x8*)(&Fl[c][kk * 32 + 8 * g]);
        acc2[0] = MFMA16(a, wf2[0][kk], acc2[0]);
        acc2[1] = MFMA16(a, wf2[1][kk], acc2[1]);
    }
#pragma unroll
    for (int nt = 0; nt < 2; ++nt) {
        int col = w * 32 + nt * 16 + c;
        float bb = b2[col];
#pragma unroll
        for (int r = 0; r < 4; ++r) {
            size_t o = (size_t)(row0 + 4 * g + r) * DMODEL + col;
            out[o] = acc2[nt][r] + bb + xpe[o];
        }
    }
}

// ---------------------------------------------------------------------------
extern "C" void kernel_launch(void* const* d_in, const int* in_sizes, int n_in,
                              void* d_out, int out_size, void* d_ws, size_t ws_size,
                              hipStream_t stream) {
    const float* x  = (const float*)d_in[0];
    const float* WQ = (const float*)d_in[1];
    const float* WK = (const float*)d_in[2];
    const float* WV = (const float*)d_in[3];
    const float* W1 = (const float*)d_in[4];
    const float* b1 = (const float*)d_in[5];
    const float* W2 = (const float*)d_in[6];
    const float* b2 = (const float*)d_in[7];
    float* out = (float*)d_out;

    const size_t NTD = (size_t)BATCH * T_SEQ * DMODEL;   // 1048576
    float* xpe   = (float*)d_ws;
    short* xpe16 = (short*)(xpe + NTD);
    short* Qh    = xpe16 + NTD;
    short* Kh    = Qh + NTD;
    short* Vs    = Kh + NTD;
    short* AObf  = Vs + NTD;
    short* Wqkvt = AObf + NTD;
    short* W1t   = Wqkvt + 3 * 16384;
    short* W2t   = W1t + 65536;

    k_pre<<<dim3(1216), dim3(256), 0, stream>>>(x, WQ, WK, WV, W1, W2,
                                                xpe, xpe16, Wqkvt, W1t, W2t);

    k_qkv<<<dim3(128, 3), dim3(256), 0, stream>>>(xpe16, Wqkvt, Qh, Kh, Vs);

    k_csum<<<dim3(16, 32), dim3(512), 0, stream>>>(Qh, Kh, Vs);

    k_attn<<<dim3(16, 32), dim3(512), 0, stream>>>(Qh, Kh, Vs, AObf);

    k_ff<<<dim3(512), dim3(256), 0, stream>>>(AObf, W1t, b1, W2t, b2, xpe, out);
}

// Round 12
// 64.396 us; speedup vs baseline: 1.3771x; 1.3024x over previous
//
#include <hip/hip_runtime.h>
#include <math.h>
#include <stdint.h>

#define T_SEQ 2048
#define BATCH 4
#define DMODEL 128
#define DFF 512
#define NHEAD 8
#define EHEAD 16

#define QSCALE (0.022097086912079608f * 1.4426950408889634f)   // rsqrt(T) * log2(e)

typedef __attribute__((ext_vector_type(8))) short bf16x8;
typedef __attribute__((ext_vector_type(4))) short bf16x4;
typedef __attribute__((ext_vector_type(4))) float f32x4;

__device__ __forceinline__ short f2bf(float f) {            // RNE
    uint32_t u = __float_as_uint(f);
    u = u + 0x7FFF + ((u >> 16) & 1);
    return (short)(u >> 16);
}
__device__ __forceinline__ short bftrunc(float f) {         // truncate (cheap)
    return (short)(__float_as_uint(f) >> 16);
}
__device__ __forceinline__ float bf2f(short s) {
    return __uint_as_float(((uint32_t)(unsigned short)s) << 16);
}
__device__ __forceinline__ float exp2_fast(float x) {       // raw v_exp_f32
#if __has_builtin(__builtin_amdgcn_exp2f)
    return __builtin_amdgcn_exp2f(x);
#else
    float r; asm("v_exp_f32 %0, %1" : "=v"(r) : "v"(x)); return r;
#endif
}

#define MFMA16(A, B, C) __builtin_amdgcn_mfma_f32_16x16x32_bf16(A, B, C, 0, 0, 0)

__device__ __forceinline__ void gload16(const void* g, void* l) {
    __builtin_amdgcn_global_load_lds(
        (const __attribute__((address_space(1))) void*)g,
        (__attribute__((address_space(3))) void*)l, 16, 0, 0);
}

// anti-correlated pairing: IDs c and c+256 -> ranks c and 511-c, so the two
// blocks co-resident on a CU have complementary (long+short) workloads.
__device__ __forceinline__ int pair_rank(int id) {
    return (id < 256) ? id : 767 - id;
}

// ---------------------------------------------------------------------------
// K0: xpe = x + PE (PE computed once per (t, f-pair), broadcast over batch);
// transpose+convert all weights to bf16.
// ---------------------------------------------------------------------------
__global__ __launch_bounds__(256) void k_pre(const float* __restrict__ x,
                                             const float* __restrict__ WQ,
                                             const float* __restrict__ WK,
                                             const float* __restrict__ WV,
                                             const float* __restrict__ W1,
                                             const float* __restrict__ W2,
                                             float* __restrict__ xpe,
                                             short* __restrict__ xpe16,
                                             short* __restrict__ Wqkvt,
                                             short* __restrict__ W1t,
                                             short* __restrict__ W2t) {
    int bid = blockIdx.x;
    int tid = threadIdx.x;
    if (bid < 512) {                        // PE over T*(D/2) = 131072 pairs
        int idx = bid * 256 + tid;
        int t = idx >> 6, fp = idx & 63;
        float dv = __expf(-(float)(2 * fp) * (9.210340371976184f / 128.0f));
        float ang = (float)t * dv;
        float sn = __sinf(ang), cs = __cosf(ang);
#pragma unroll
        for (int b = 0; b < 4; ++b) {
            size_t base = ((size_t)b * T_SEQ + t) * 128 + 2 * fp;
            float2 xv = *(const float2*)(x + base);
            float v0 = xv.x + sn, v1 = xv.y + cs;
            *(float2*)(xpe + base) = make_float2(v0, v1);
            uint32_t pk = (uint32_t)(unsigned short)f2bf(v0) |
                          ((uint32_t)(unsigned short)f2bf(v1) << 16);
            *(uint32_t*)(xpe16 + base) = pk;
        }
    } else if (bid < 704) {                 // WQ/WK/WV -> [n][k] bf16
        int m = (bid - 512) >> 6;
        int o = ((bid - 512) & 63) * 256 + tid;       // 0..16383
        int n = o >> 7, k = o & 127;
        const float* W = (m == 0) ? WQ : (m == 1) ? WK : WV;
        Wqkvt[m * 16384 + o] = f2bf(W[k * 128 + n]);
    } else if (bid < 960) {                 // W1 [128][512] -> W1t [512][128]
        int o = (bid - 704) * 256 + tid;    // 0..65535
        int n = o >> 7, k = o & 127;
        W1t[o] = f2bf(W1[k * 512 + n]);
    } else {                                // W2 [512][128] -> W2t [128][512]
        int o = (bid - 960) * 256 + tid;    // 0..65535
        int n = o >> 9, k = o & 511;
        W2t[o] = f2bf(W2[k * 128 + n]);
    }
}

// ---------------------------------------------------------------------------
// K1: QKV projection: bf16 MFMA GEMM, W in registers (Wt[n][k] bf16).
// z=0: Qh[hb][t][16] *= QSCALE; z=1: Kh[hb][t][16]; z=2: Vs[hb][e][T]
// ---------------------------------------------------------------------------
__global__ __launch_bounds__(256) void k_qkv(const short* __restrict__ xpe16,
                                             const short* __restrict__ Wqkvt,
                                             short* __restrict__ Qh,
                                             short* __restrict__ Kh,
                                             short* __restrict__ Vs) {
    int z = blockIdx.y;
    const short* Wt = Wqkvt + z * 16384;
    int wave = threadIdx.x >> 6, lane = threadIdx.x & 63;
    int g = lane >> 4, c = lane & 15;
    int row0 = blockIdx.x * 64 + wave * 16;

    bf16x8 wf[8][4];
#pragma unroll
    for (int nt = 0; nt < 8; ++nt)
#pragma unroll
        for (int kk = 0; kk < 4; ++kk)
            wf[nt][kk] = *(const bf16x8*)(Wt + (nt * 16 + c) * 128 + kk * 32 + 8 * g);

    bf16x8 af[4];
#pragma unroll
    for (int kk = 0; kk < 4; ++kk)
        af[kk] = *(const bf16x8*)(xpe16 + (size_t)(row0 + c) * 128 + kk * 32 + 8 * g);

    f32x4 acc[8];
#pragma unroll
    for (int nt = 0; nt < 8; ++nt) acc[nt] = (f32x4){0.f, 0.f, 0.f, 0.f};
#pragma unroll
    for (int kk = 0; kk < 4; ++kk)
#pragma unroll
        for (int nt = 0; nt < 8; ++nt)
            acc[nt] = MFMA16(af[kk], wf[nt][kk], acc[nt]);

    int b = row0 >> 11;
    int t0 = (row0 & (T_SEQ - 1)) + 4 * g;
    if (z < 2) {
        short* dst = (z == 0) ? Qh : Kh;
        float sc = (z == 0) ? QSCALE : 1.0f;
#pragma unroll
        for (int nt = 0; nt < 8; ++nt) {
            int hb = nt * 4 + b;
#pragma unroll
            for (int r = 0; r < 4; ++r)
                dst[(size_t)(hb * T_SEQ + t0 + r) * 16 + c] = f2bf(acc[nt][r] * sc);
        }
    } else {
#pragma unroll
        for (int nt = 0; nt < 8; ++nt) {
            int hb = nt * 4 + b;
            bf16x4 v;
#pragma unroll
            for (int r = 0; r < 4; ++r) v[r] = f2bf(acc[nt][r]);
            *(bf16x4*)(Vs + (size_t)(hb * 16 + c) * T_SEQ + t0) = v;
        }
    }
}

// ---------------------------------------------------------------------------
// K2: column softmax denominators + V scaling. 512-thr blocks (8 waves).
// Flat grid 512, rank = pair_rank(id): kc = rank>>5 (0 = longest), hb = rank&31.
// Wave w = (strip s=w&3 -> 32 cols, half h=w>>2 -> q-slots {4h..4h+3} of each
// staged 256-q tile). Partial sums combined via LDS; block scales Vs cols.
// ---------------------------------------------------------------------------
__global__ __launch_bounds__(512, 4) void k_csum(const short* __restrict__ Qh,
                                                 const short* __restrict__ Kh,
                                                 short* __restrict__ Vs) {
    __shared__ __align__(16) short Qt[2][4096];
    __shared__ float csLds[8][32];
    __shared__ float invl[128];
    const bf16x8 zz = {0, 0, 0, 0, 0, 0, 0, 0};
    const f32x4 z = {0.f, 0.f, 0.f, 0.f};

    int rank = pair_rank((int)blockIdx.x);
    int kc = rank >> 5, hb = rank & 31;
    int tid = threadIdx.x;
    int wave = tid >> 6, lane = tid & 63;
    int g = lane >> 4, c = lane & 15;
    int s = wave & 3, h = wave >> 2;
    int kw = kc * 128 + s * 32;
    const size_t hbT = (size_t)hb * T_SEQ;
    const short* Qg = Qh + hbT * 16;

    bf16x8 kfA = zz, kfB = zz;
    if (g < 2) {
        kfA = *(const bf16x8*)(Kh + (hbT + kw + c) * 16 + 8 * g);
        kfB = *(const bf16x8*)(Kh + (hbT + kw + 16 + c) * 16 + 8 * g);
    }

    int tstart = kc >> 1;                   // first 256-q tile with q >= kc*128
    gload16(Qg + (size_t)tstart * 4096 + tid * 8, &Qt[0][tid * 8]);
    __syncthreads();

    float csA = 0.f, csB = 0.f;
    for (int t = tstart; t < 8; ++t) {
        int buf = (t - tstart) & 1;
        if (t + 1 < 8)
            gload16(Qg + (size_t)(t + 1) * 4096 + tid * 8, &Qt[buf ^ 1][tid * 8]);
        const short* Qtb = &Qt[buf][0];
#pragma unroll
        for (int sj = 0; sj < 4; ++sj) {
            int ss = 4 * h + sj;
            int q32 = t * 256 + ss * 32;
            if (q32 + 31 < kw) continue;            // fully above diagonal
            bf16x8 qfa = zz, qfb = zz;
            if (g < 2) {
                qfa = *(const bf16x8*)(Qtb + (ss * 32 + c) * 16 + g * 8);
                qfb = *(const bf16x8*)(Qtb + (ss * 32 + 16 + c) * 16 + g * 8);
            }
            f32x4 sA1 = MFMA16(qfa, kfA, z);
            f32x4 sB1 = MFMA16(qfa, kfB, z);
            f32x4 sA2 = MFMA16(qfb, kfA, z);
            f32x4 sB2 = MFMA16(qfb, kfB, z);
            if (q32 >= kw + 32) {                   // fully below diagonal
#pragma unroll
                for (int r = 0; r < 4; ++r) {
                    csA += exp2_fast(sA1[r]) + exp2_fast(sA2[r]);
                    csB += exp2_fast(sB1[r]) + exp2_fast(sB2[r]);
                }
            } else {                                // diagonal region: mask
                int kA = kw + c, kB = kw + 16 + c;
#pragma unroll
                for (int r = 0; r < 4; ++r) {
                    int qa = q32 + 4 * g + r, qb = q32 + 16 + 4 * g + r;
                    csA += (qa >= kA) ? exp2_fast(sA1[r]) : 0.f;
                    csA += (qb >= kA) ? exp2_fast(sA2[r]) : 0.f;
                    csB += (qa >= kB) ? exp2_fast(sB1[r]) : 0.f;
                    csB += (qb >= kB) ? exp2_fast(sB2[r]) : 0.f;
                }
            }
        }
        __syncthreads();
    }

    csA += __shfl_xor(csA, 16);
    csA += __shfl_xor(csA, 32);
    csB += __shfl_xor(csB, 16);
    csB += __shfl_xor(csB, 32);
    if (lane < 32) csLds[wave][lane] = (lane < 16) ? csA : csB;
    __syncthreads();
    if (tid < 128) {                        // strip = tid>>5, col-in-strip = tid&31
        int st = tid >> 5, col = tid & 31;
        invl[st * 32 + col] = 1.0f / (csLds[st][col] + csLds[st + 4][col]);
    }
    __syncthreads();
    if (tid < 256) {                        // scale V cols [kc*128, +128)
        int e = tid >> 4, kcol = (tid & 15) * 8;
        size_t vo = (size_t)(hb * 16 + e) * T_SEQ + kc * 128 + kcol;
        bf16x8 v = *(bf16x8*)(Vs + vo);
        bf16x8 o;
#pragma unroll
        for (int j = 0; j < 8; ++j) o[j] = f2bf(bf2f(v[j]) * invl[kcol + j]);
        *(bf16x8*)(Vs + vo) = o;
    }
}

// ---------------------------------------------------------------------------
// K3: attention output. 512-thr blocks (8 waves). Flat grid 512,
// rank = pair_rank(id): qn = 15 - (rank>>5) (rank 0 = longest), hb = rank&31.
// Wave w = (strip s=w&3 -> q0w = qn*128+s*32, half h=w>>2 -> k-slots
// {4h..4h+3} of each staged 256-k tile). K linear + V e-major XOR-swizzled
// tiles double-buffered via global_load_lds. Partial O combined via LDS.
// ---------------------------------------------------------------------------
__global__ __launch_bounds__(512, 4) void k_attn(const short* __restrict__ Qh,
                                                 const short* __restrict__ Kh,
                                                 const short* __restrict__ Vs,
                                                 short* __restrict__ AObf) {
    __shared__ __align__(16) short Kt[2][4096];
    __shared__ __align__(16) short Vt[2][4096];
    const bf16x8 zz = {0, 0, 0, 0, 0, 0, 0, 0};
    const f32x4 z = {0.f, 0.f, 0.f, 0.f};

    int rank = pair_rank((int)blockIdx.x);
    int qn = 15 - (rank >> 5), hb = rank & 31;
    int h2 = hb >> 2, b = hb & 3;
    int tid = threadIdx.x;
    int wave = tid >> 6, lane = tid & 63;
    int g = lane >> 4, c = lane & 15;
    int s = wave & 3, h = wave >> 2;
    int q0w = qn * 128 + s * 32;
    const size_t hbT = (size_t)hb * T_SEQ;
    const short* Kg = Kh + hbT * 16;
    const short* Vg = Vs + (size_t)hb * 16 * T_SEQ;

    bf16x8 qf0 = zz, qf1 = zz;
    if (g < 2) {
        qf0 = *(const bf16x8*)(Qh + (hbT + q0w + c) * 16 + 8 * g);
        qf1 = *(const bf16x8*)(Qh + (hbT + q0w + 16 + c) * 16 + 8 * g);
    }

    int nT = (qn >> 1) + 1;                 // 256-k tiles this block touches

#define STAGE(bf, kt)                                                        \
    do {                                                                     \
        int k0s = (kt) * 256;                                                \
        gload16(Kg + (size_t)k0s * 16 + tid * 8, &Kt[bf][tid * 8]);          \
        int e0 = tid >> 5, jp = tid & 31, j0 = jp ^ (e0 & 7);                \
        gload16(Vg + (size_t)e0 * T_SEQ + k0s + j0 * 8, &Vt[bf][tid * 8]);   \
    } while (0)

    STAGE(0, 0);
    __syncthreads();

    f32x4 acc0 = z, acc1 = z;
    for (int t = 0; t < nT; ++t) {
        int buf = t & 1;
        if (t + 1 < nT) STAGE(buf ^ 1, t + 1);
        const short* Ktb = &Kt[buf][0];
        const short* Vtb = &Vt[buf][0];
#pragma unroll
        for (int sj = 0; sj < 4; ++sj) {
            int ss = 4 * h + sj;
            int k32 = t * 256 + ss * 32;
            if (k32 > q0w + 31) continue;           // above causal range
            bf16x8 kf0 = zz, kf1 = zz;
            if (g < 2) {
                kf0 = *(const bf16x8*)(Ktb + (ss * 32 + c) * 16 + g * 8);
                kf1 = *(const bf16x8*)(Ktb + (ss * 32 + 16 + c) * 16 + g * 8);
            }
            int ja = ss * 4 + (g >> 1);             // granule in 32-granule row
            const short* vrow = Vtb + c * 256 + ((g & 1) << 2);
            bf16x4 v0 = *(const bf16x4*)(vrow + ((ja ^ (c & 7)) << 3));
            bf16x4 v1 = *(const bf16x4*)(vrow + (((ja + 2) ^ (c & 7)) << 3));
            f32x4 s0 = MFMA16(kf0, qf0, z);
            f32x4 s1 = MFMA16(kf1, qf0, z);
            f32x4 s2 = MFMA16(kf0, qf1, z);
            f32x4 s3 = MFMA16(kf1, qf1, z);
            bf16x8 aA, aB, vf;
            if (k32 + 31 <= q0w) {                  // full pair, no masking
#pragma unroll
                for (int r = 0; r < 4; ++r) {
                    aA[r] = bftrunc(exp2_fast(s0[r]));
                    aA[4 + r] = bftrunc(exp2_fast(s1[r]));
                    aB[r] = bftrunc(exp2_fast(s2[r]));
                    aB[4 + r] = bftrunc(exp2_fast(s3[r]));
                    vf[r] = v0[r];
                    vf[4 + r] = v1[r];
                }
            } else {                                // causal boundary: mask
                int qa = q0w + c, qb = q0w + 16 + c;
                int ka = k32 + 4 * g, kb = k32 + 16 + 4 * g;
#pragma unroll
                for (int r = 0; r < 4; ++r) {
                    aA[r] = (ka + r <= qa) ? bftrunc(exp2_fast(s0[r])) : (short)0;
                    aA[4 + r] = (kb + r <= qa) ? bftrunc(exp2_fast(s1[r])) : (short)0;
                    aB[r] = (ka + r <= qb) ? bftrunc(exp2_fast(s2[r])) : (short)0;
                    aB[4 + r] = (kb + r <= qb) ? bftrunc(exp2_fast(s3[r])) : (short)0;
                    vf[r] = v0[r];
                    vf[4 + r] = v1[r];
                }
            }
            acc0 = MFMA16(aA, vf, acc0);
            acc1 = MFMA16(aB, vf, acc1);
        }
        __syncthreads();
    }
#undef STAGE

    // combine halves: h=1 waves dump partials to LDS, h=0 waves add and store.
    float* Of = (float*)&Kt[0][0];          // 8 KB, staging done
    if (h == 1) {
#pragma unroll
        for (int r = 0; r < 4; ++r) {
            Of[r * 256 + s * 64 + lane] = acc0[r];
            Of[(4 + r) * 256 + s * 64 + lane] = acc1[r];
        }
    }
    __syncthreads();
    if (h == 0) {
#pragma unroll
        for (int r = 0; r < 4; ++r) {
            acc0[r] += Of[r * 256 + s * 64 + lane];
            acc1[r] += Of[(4 + r) * 256 + s * 64 + lane];
        }
#pragma unroll
        for (int r = 0; r < 4; ++r) {
            AObf[(size_t)(b * T_SEQ + q0w + 4 * g + r) * DMODEL + h2 * EHEAD + c] = f2bf(acc0[r]);
            AObf[(size_t)(b * T_SEQ + q0w + 16 + 4 * g + r) * DMODEL + h2 * EHEAD + c] = f2bf(acc1[r]);
        }
    }
}

// ---------------------------------------------------------------------------
// K4: fused FF: out = relu(AO@W1+b1)@W2 + b2 + xpe.
// Grid 256 blocks x 256 thr; block owns 32 rows (2 chunks of 16), weights
// loaded into registers ONCE and reused across chunks (halves L2 W-traffic).
// Phase 1: wave w computes F cols [w*128,+128) for both chunks -> LDS
// (32 x 516 padded). Phase 2: wave w computes out cols [w*32,+32).
// ---------------------------------------------------------------------------
__global__ __launch_bounds__(256) void k_ff(const short* __restrict__ AObf,
                                            const short* __restrict__ W1t,
                                            const float* __restrict__ b1,
                                            const short* __restrict__ W2t,
                                            const float* __restrict__ b2,
                                            const float* __restrict__ xpe,
                                            float* __restrict__ out) {
    __shared__ __align__(16) short Fl[32][516];
    int w = threadIdx.x >> 6, lane = threadIdx.x & 63;
    int g = lane >> 4, c = lane & 15;
    int row0 = blockIdx.x * 32;

    // ---- phase 1: F[r][w*128 + n] = relu(AO @ W1 + b1), 2 chunks ----
    {
        bf16x8 wf[8][4];
#pragma unroll
        for (int nt = 0; nt < 8; ++nt)
#pragma unroll
            for (int kk = 0; kk < 4; ++kk)
                wf[nt][kk] = *(const bf16x8*)(W1t + (w * 128 + nt * 16 + c) * 128 + kk * 32 + 8 * g);

#pragma unroll
        for (int ch = 0; ch < 2; ++ch) {
            int rbase = row0 + ch * 16;
            bf16x8 af[4];
#pragma unroll
            for (int kk = 0; kk < 4; ++kk)
                af[kk] = *(const bf16x8*)(AObf + (size_t)(rbase + c) * 128 + kk * 32 + 8 * g);

            f32x4 acc[8];
#pragma unroll
            for (int nt = 0; nt < 8; ++nt) acc[nt] = (f32x4){0.f, 0.f, 0.f, 0.f};
#pragma unroll
            for (int kk = 0; kk < 4; ++kk)
#pragma unroll
                for (int nt = 0; nt < 8; ++nt)
                    acc[nt] = MFMA16(af[kk], wf[nt][kk], acc[nt]);

#pragma unroll
            for (int nt = 0; nt < 8; ++nt) {
                int col = w * 128 + nt * 16 + c;
                float bb = b1[col];
#pragma unroll
                for (int r = 0; r < 4; ++r)
                    Fl[ch * 16 + 4 * g + r][col] = f2bf(fmaxf(acc[nt][r] + bb, 0.f));
            }
        }
    }
    __syncthreads();

    // ---- phase 2: out cols [w*32, +32) = F @ W2 + b2 + xpe, 2 chunks ----
    bf16x8 wf2[2][16];
#pragma unroll
    for (int nt = 0; nt < 2; ++nt)
#pragma unroll
        for (int kk = 0; kk < 16; ++kk)
            wf2[nt][kk] = *(const bf16x8*)(W2t + (w * 32 + nt * 16 + c) * 512 + kk * 32 + 8 * g);

#pragma unroll
    for (int ch = 0; ch < 2; ++ch) {
        int rbase = row0 + ch * 16;
        f32x4 acc2[2];
        acc2[0] = (f32x4){0.f, 0.f, 0.f, 0.f};
        acc2[1] = (f32x4){0.f, 0.f, 0.f, 0.f};
#pragma unroll
        for (int kk = 0; kk < 16; ++kk) {
            bf16x8 a = *(const bf16x8*)(&Fl[ch * 16 + c][kk * 32 + 8 * g]);
            acc2[0] = MFMA16(a, wf2[0][kk], acc2[0]);
            acc2[1] = MFMA16(a, wf2[1][kk], acc2[1]);
        }
#pragma unroll
        for (int nt = 0; nt < 2; ++nt) {
            int col = w * 32 + nt * 16 + c;
            float bb = b2[col];
#pragma unroll
            for (int r = 0; r < 4; ++r) {
                size_t o = (size_t)(rbase + 4 * g + r) * DMODEL + col;
                out[o] = acc2[nt][r] + bb + xpe[o];
            }
        }
    }
}

// ---------------------------------------------------------------------------
extern "C" void kernel_launch(void* const* d_in, const int* in_sizes, int n_in,
                              void* d_out, int out_size, void* d_ws, size_t ws_size,
                              hipStream_t stream) {
    const float* x  = (const float*)d_in[0];
    const float* WQ = (const float*)d_in[1];
    const float* WK = (const float*)d_in[2];
    const float* WV = (const float*)d_in[3];
    const float* W1 = (const float*)d_in[4];
    const float* b1 = (const float*)d_in[5];
    const float* W2 = (const float*)d_in[6];
    const float* b2 = (const float*)d_in[7];
    float* out = (float*)d_out;

    const size_t NTD = (size_t)BATCH * T_SEQ * DMODEL;   // 1048576
    float* xpe   = (float*)d_ws;
    short* xpe16 = (short*)(xpe + NTD);
    short* Qh    = xpe16 + NTD;
    short* Kh    = Qh + NTD;
    short* Vs    = Kh + NTD;
    short* AObf  = Vs + NTD;
    short* Wqkvt = AObf + NTD;
    short* W1t   = Wqkvt + 3 * 16384;
    short* W2t   = W1t + 65536;

    k_pre<<<dim3(1216), dim3(256), 0, stream>>>(x, WQ, WK, WV, W1, W2,
                                                xpe, xpe16, Wqkvt, W1t, W2t);

    k_qkv<<<dim3(128, 3), dim3(256), 0, stream>>>(xpe16, Wqkvt, Qh, Kh, Vs);

    k_csum<<<dim3(512), dim3(512), 0, stream>>>(Qh, Kh, Vs);

    k_attn<<<dim3(512), dim3(512), 0, stream>>>(Qh, Kh, Vs, AObf);

    k_ff<<<dim3(256), dim3(256), 0, stream>>>(AObf, W1t, b1, W2t, b2, xpe, out);
}

// Round 13
// 59.531 us; speedup vs baseline: 1.4897x; 1.0817x over previous
//
#include <hip/hip_runtime.h>
#include <math.h>
#include <stdint.h>

#define T_SEQ 2048
#define BATCH 4
#define DMODEL 128
#define DFF 512
#define NHEAD 8
#define EHEAD 16

#define QSCALE (0.022097086912079608f * 1.4426950408889634f)   // rsqrt(T) * log2(e)

typedef __attribute__((ext_vector_type(8))) short bf16x8;
typedef __attribute__((ext_vector_type(4))) short bf16x4;
typedef __attribute__((ext_vector_type(4))) float f32x4;

__device__ __forceinline__ short f2bf(float f) {            // RNE
    uint32_t u = __float_as_uint(f);
    u = u + 0x7FFF + ((u >> 16) & 1);
    return (short)(u >> 16);
}
__device__ __forceinline__ short bftrunc(float f) {         // truncate (cheap)
    return (short)(__float_as_uint(f) >> 16);
}
__device__ __forceinline__ float bf2f(short s) {
    return __uint_as_float(((uint32_t)(unsigned short)s) << 16);
}
__device__ __forceinline__ float exp2_fast(float x) {       // raw v_exp_f32
#if __has_builtin(__builtin_amdgcn_exp2f)
    return __builtin_amdgcn_exp2f(x);
#else
    float r; asm("v_exp_f32 %0, %1" : "=v"(r) : "v"(x)); return r;
#endif
}

#define MFMA16(A, B, C) __builtin_amdgcn_mfma_f32_16x16x32_bf16(A, B, C, 0, 0, 0)

__device__ __forceinline__ void gload16(const void* g, void* l) {
    __builtin_amdgcn_global_load_lds(
        (const __attribute__((address_space(1))) void*)g,
        (__attribute__((address_space(3))) void*)l, 16, 0, 0);
}

// anti-correlated pairing: IDs c and c+256 -> ranks c and 511-c, so the two
// blocks co-resident on a CU have complementary (long+short) workloads.
__device__ __forceinline__ int pair_rank(int id) {
    return (id < 256) ? id : 767 - id;
}

// ---------------------------------------------------------------------------
// K1: fused prep + QKV projection. Grid (128, 4), block 256.
// z<3: block owns 64 rows; computes x+PE inline (A-fragments in registers,
//      z=0 also writes fp32 xpe for the residual), converts its W to a
//      bf16-transposed LDS tile (pad-136 rows, conflict-free b128 reads),
//      then MFMA GEMM. z=0: Qh *= QSCALE; z=1: Kh; z=2: Vs[hb][e][T].
// z=3: 128 trivial blocks convert W1->W1t, W2->W2t for k_ff (consumed by a
//      LATER launch only -- no same-launch dependency).
// ---------------------------------------------------------------------------
#define WP 136      // padded LDS row stride (shorts): 272 B, 16B-aligned
__global__ __launch_bounds__(256) void k_qkv(const float* __restrict__ x,
                                             const float* __restrict__ WQ,
                                             const float* __restrict__ WK,
                                             const float* __restrict__ WV,
                                             const float* __restrict__ W1,
                                             const float* __restrict__ W2,
                                             float* __restrict__ xpe,
                                             short* __restrict__ Qh,
                                             short* __restrict__ Kh,
                                             short* __restrict__ Vs,
                                             short* __restrict__ W1t,
                                             short* __restrict__ W2t) {
    __shared__ __align__(16) short Wlds[128 * WP];
    int z = blockIdx.y;
    int tid = threadIdx.x;

    if (z == 3) {                           // W1/W2 -> bf16 transposed
        int base = (int)blockIdx.x * 256 + tid;      // 0..32767
#pragma unroll
        for (int i = 0; i < 2; ++i) {
            int o = base + i * 32768;                // W1t: 65536 = n*128+k
            int n = o >> 7, k = o & 127;
            W1t[o] = f2bf(W1[k * 512 + n]);
        }
#pragma unroll
        for (int i = 0; i < 2; ++i) {
            int o = base + i * 32768;                // W2t: 65536 = n*512+k
            int n = o >> 9, k = o & 511;
            W2t[o] = f2bf(W2[k * 128 + n]);
        }
        return;
    }

    int wave = tid >> 6, lane = tid & 63;
    int g = lane >> 4, c = lane & 15;
    int row0 = blockIdx.x * 64 + wave * 16;
    int row = row0 + c;
    int tloc = row & (T_SEQ - 1);

    // ---- stage W^T (bf16) into LDS: thread owns k-row (tid&127), 64 n's ----
    {
        const float* Wsrc = (z == 0) ? WQ : (z == 1) ? WK : WV;
        int k = tid & 127, n0 = (tid >> 7) * 64;
        const float* src = Wsrc + k * 128 + n0;
#pragma unroll
        for (int j = 0; j < 64; j += 4) {
            float4 wv = *(const float4*)(src + j);
            Wlds[(n0 + j + 0) * WP + k] = f2bf(wv.x);
            Wlds[(n0 + j + 1) * WP + k] = f2bf(wv.y);
            Wlds[(n0 + j + 2) * WP + k] = f2bf(wv.z);
            Wlds[(n0 + j + 3) * WP + k] = f2bf(wv.w);
        }
    }

    // ---- A-fragments: af = bf16(x + PE); z=0 writes fp32 xpe ----
    bf16x8 af[4];
#pragma unroll
    for (int kk = 0; kk < 4; ++kk) {
        int d0 = kk * 32 + 8 * g;
        const float* xb = x + (size_t)row * 128 + d0;
        float4 xa = *(const float4*)(xb);
        float4 xc = *(const float4*)(xb + 4);
        float vv[8] = {xa.x, xa.y, xa.z, xa.w, xc.x, xc.y, xc.z, xc.w};
#pragma unroll
        for (int p = 0; p < 4; ++p) {
            int d = d0 + 2 * p;
            float dv = __expf(-(float)d * (9.210340371976184f / 128.0f));
            float ang = (float)tloc * dv;
            vv[2 * p] += __sinf(ang);
            vv[2 * p + 1] += __cosf(ang);
        }
        if (z == 0) {
            float* xo = xpe + (size_t)row * 128 + d0;
            *(float4*)(xo) = make_float4(vv[0], vv[1], vv[2], vv[3]);
            *(float4*)(xo + 4) = make_float4(vv[4], vv[5], vv[6], vv[7]);
        }
#pragma unroll
        for (int j = 0; j < 8; ++j) af[kk][j] = f2bf(vv[j]);
    }
    __syncthreads();

    // ---- W fragments from LDS + MFMA ----
    bf16x8 wf[8][4];
#pragma unroll
    for (int nt = 0; nt < 8; ++nt)
#pragma unroll
        for (int kk = 0; kk < 4; ++kk)
            wf[nt][kk] = *(const bf16x8*)(&Wlds[(nt * 16 + c) * WP + kk * 32 + 8 * g]);

    f32x4 acc[8];
#pragma unroll
    for (int nt = 0; nt < 8; ++nt) acc[nt] = (f32x4){0.f, 0.f, 0.f, 0.f};
#pragma unroll
    for (int kk = 0; kk < 4; ++kk)
#pragma unroll
        for (int nt = 0; nt < 8; ++nt)
            acc[nt] = MFMA16(af[kk], wf[nt][kk], acc[nt]);

    int b = row0 >> 11;
    int t0 = (row0 & (T_SEQ - 1)) + 4 * g;
    if (z < 2) {
        short* dst = (z == 0) ? Qh : Kh;
        float sc = (z == 0) ? QSCALE : 1.0f;
#pragma unroll
        for (int nt = 0; nt < 8; ++nt) {
            int hb = nt * 4 + b;
#pragma unroll
            for (int r = 0; r < 4; ++r)
                dst[(size_t)(hb * T_SEQ + t0 + r) * 16 + c] = f2bf(acc[nt][r] * sc);
        }
    } else {
#pragma unroll
        for (int nt = 0; nt < 8; ++nt) {
            int hb = nt * 4 + b;
            bf16x4 v;
#pragma unroll
            for (int r = 0; r < 4; ++r) v[r] = f2bf(acc[nt][r]);
            *(bf16x4*)(Vs + (size_t)(hb * 16 + c) * T_SEQ + t0) = v;
        }
    }
}
#undef WP

// ---------------------------------------------------------------------------
// K2: column softmax denominators + V scaling. 512-thr blocks (8 waves).
// Flat grid 512, rank = pair_rank(id): kc = rank>>5 (0 = longest), hb = rank&31.
// Wave w = (strip s=w&3 -> 32 cols, half h=w>>2 -> q-slots {4h..4h+3} of each
// staged 256-q tile). Partial sums combined via LDS; block scales Vs cols.
// ---------------------------------------------------------------------------
__global__ __launch_bounds__(512, 4) void k_csum(const short* __restrict__ Qh,
                                                 const short* __restrict__ Kh,
                                                 short* __restrict__ Vs) {
    __shared__ __align__(16) short Qt[2][4096];
    __shared__ float csLds[8][32];
    __shared__ float invl[128];
    const bf16x8 zz = {0, 0, 0, 0, 0, 0, 0, 0};
    const f32x4 z = {0.f, 0.f, 0.f, 0.f};

    int rank = pair_rank((int)blockIdx.x);
    int kc = rank >> 5, hb = rank & 31;
    int tid = threadIdx.x;
    int wave = tid >> 6, lane = tid & 63;
    int g = lane >> 4, c = lane & 15;
    int s = wave & 3, h = wave >> 2;
    int kw = kc * 128 + s * 32;
    const size_t hbT = (size_t)hb * T_SEQ;
    const short* Qg = Qh + hbT * 16;

    bf16x8 kfA = zz, kfB = zz;
    if (g < 2) {
        kfA = *(const bf16x8*)(Kh + (hbT + kw + c) * 16 + 8 * g);
        kfB = *(const bf16x8*)(Kh + (hbT + kw + 16 + c) * 16 + 8 * g);
    }

    int tstart = kc >> 1;                   // first 256-q tile with q >= kc*128
    gload16(Qg + (size_t)tstart * 4096 + tid * 8, &Qt[0][tid * 8]);
    __syncthreads();

    float csA = 0.f, csB = 0.f;
    for (int t = tstart; t < 8; ++t) {
        int buf = (t - tstart) & 1;
        if (t + 1 < 8)
            gload16(Qg + (size_t)(t + 1) * 4096 + tid * 8, &Qt[buf ^ 1][tid * 8]);
        const short* Qtb = &Qt[buf][0];
#pragma unroll
        for (int sj = 0; sj < 4; ++sj) {
            int ss = 4 * h + sj;
            int q32 = t * 256 + ss * 32;
            if (q32 + 31 < kw) continue;            // fully above diagonal
            bf16x8 qfa = zz, qfb = zz;
            if (g < 2) {
                qfa = *(const bf16x8*)(Qtb + (ss * 32 + c) * 16 + g * 8);
                qfb = *(const bf16x8*)(Qtb + (ss * 32 + 16 + c) * 16 + g * 8);
            }
            f32x4 sA1 = MFMA16(qfa, kfA, z);
            f32x4 sB1 = MFMA16(qfa, kfB, z);
            f32x4 sA2 = MFMA16(qfb, kfA, z);
            f32x4 sB2 = MFMA16(qfb, kfB, z);
            if (q32 >= kw + 32) {                   // fully below diagonal
#pragma unroll
                for (int r = 0; r < 4; ++r) {
                    csA += exp2_fast(sA1[r]) + exp2_fast(sA2[r]);
                    csB += exp2_fast(sB1[r]) + exp2_fast(sB2[r]);
                }
            } else {                                // diagonal region: mask
                int kA = kw + c, kB = kw + 16 + c;
#pragma unroll
                for (int r = 0; r < 4; ++r) {
                    int qa = q32 + 4 * g + r, qb = q32 + 16 + 4 * g + r;
                    csA += (qa >= kA) ? exp2_fast(sA1[r]) : 0.f;
                    csA += (qb >= kA) ? exp2_fast(sA2[r]) : 0.f;
                    csB += (qa >= kB) ? exp2_fast(sB1[r]) : 0.f;
                    csB += (qb >= kB) ? exp2_fast(sB2[r]) : 0.f;
                }
            }
        }
        __syncthreads();
    }

    csA += __shfl_xor(csA, 16);
    csA += __shfl_xor(csA, 32);
    csB += __shfl_xor(csB, 16);
    csB += __shfl_xor(csB, 32);
    if (lane < 32) csLds[wave][lane] = (lane < 16) ? csA : csB;
    __syncthreads();
    if (tid < 128) {                        // strip = tid>>5, col-in-strip = tid&31
        int st = tid >> 5, col = tid & 31;
        invl[st * 32 + col] = 1.0f / (csLds[st][col] + csLds[st + 4][col]);
    }
    __syncthreads();
    if (tid < 256) {                        // scale V cols [kc*128, +128)
        int e = tid >> 4, kcol = (tid & 15) * 8;
        size_t vo = (size_t)(hb * 16 + e) * T_SEQ + kc * 128 + kcol;
        bf16x8 v = *(bf16x8*)(Vs + vo);
        bf16x8 o;
#pragma unroll
        for (int j = 0; j < 8; ++j) o[j] = f2bf(bf2f(v[j]) * invl[kcol + j]);
        *(bf16x8*)(Vs + vo) = o;
    }
}

// ---------------------------------------------------------------------------
// K3: attention output. 512-thr blocks (8 waves). Flat grid 512,
// rank = pair_rank(id): qn = 15 - (rank>>5) (rank 0 = longest), hb = rank&31.
// Wave w = (strip s=w&3 -> q0w = qn*128+s*32, half h=w>>2 -> k-slots
// {4h..4h+3} of each staged 256-k tile). K linear + V e-major XOR-swizzled
// tiles double-buffered via global_load_lds. Partial O combined via LDS.
// ---------------------------------------------------------------------------
__global__ __launch_bounds__(512, 4) void k_attn(const short* __restrict__ Qh,
                                                 const short* __restrict__ Kh,
                                                 const short* __restrict__ Vs,
                                                 short* __restrict__ AObf) {
    __shared__ __align__(16) short Kt[2][4096];
    __shared__ __align__(16) short Vt[2][4096];
    const bf16x8 zz = {0, 0, 0, 0, 0, 0, 0, 0};
    const f32x4 z = {0.f, 0.f, 0.f, 0.f};

    int rank = pair_rank((int)blockIdx.x);
    int qn = 15 - (rank >> 5), hb = rank & 31;
    int h2 = hb >> 2, b = hb & 3;
    int tid = threadIdx.x;
    int wave = tid >> 6, lane = tid & 63;
    int g = lane >> 4, c = lane & 15;
    int s = wave & 3, h = wave >> 2;
    int q0w = qn * 128 + s * 32;
    const size_t hbT = (size_t)hb * T_SEQ;
    const short* Kg = Kh + hbT * 16;
    const short* Vg = Vs + (size_t)hb * 16 * T_SEQ;

    bf16x8 qf0 = zz, qf1 = zz;
    if (g < 2) {
        qf0 = *(const bf16x8*)(Qh + (hbT + q0w + c) * 16 + 8 * g);
        qf1 = *(const bf16x8*)(Qh + (hbT + q0w + 16 + c) * 16 + 8 * g);
    }

    int nT = (qn >> 1) + 1;                 // 256-k tiles this block touches

#define STAGE(bf, kt)                                                        \
    do {                                                                     \
        int k0s = (kt) * 256;                                                \
        gload16(Kg + (size_t)k0s * 16 + tid * 8, &Kt[bf][tid * 8]);          \
        int e0 = tid >> 5, jp = tid & 31, j0 = jp ^ (e0 & 7);                \
        gload16(Vg + (size_t)e0 * T_SEQ + k0s + j0 * 8, &Vt[bf][tid * 8]);   \
    } while (0)

    STAGE(0, 0);
    __syncthreads();

    f32x4 acc0 = z, acc1 = z;
    for (int t = 0; t < nT; ++t) {
        int buf = t & 1;
        if (t + 1 < nT) STAGE(buf ^ 1, t + 1);
        const short* Ktb = &Kt[buf][0];
        const short* Vtb = &Vt[buf][0];
#pragma unroll
        for (int sj = 0; sj < 4; ++sj) {
            int ss = 4 * h + sj;
            int k32 = t * 256 + ss * 32;
            if (k32 > q0w + 31) continue;           // above causal range
            bf16x8 kf0 = zz, kf1 = zz;
            if (g < 2) {
                kf0 = *(const bf16x8*)(Ktb + (ss * 32 + c) * 16 + g * 8);
                kf1 = *(const bf16x8*)(Ktb + (ss * 32 + 16 + c) * 16 + g * 8);
            }
            int ja = ss * 4 + (g >> 1);             // granule in 32-granule row
            const short* vrow = Vtb + c * 256 + ((g & 1) << 2);
            bf16x4 v0 = *(const bf16x4*)(vrow + ((ja ^ (c & 7)) << 3));
            bf16x4 v1 = *(const bf16x4*)(vrow + (((ja + 2) ^ (c & 7)) << 3));
            f32x4 s0 = MFMA16(kf0, qf0, z);
            f32x4 s1 = MFMA16(kf1, qf0, z);
            f32x4 s2 = MFMA16(kf0, qf1, z);
            f32x4 s3 = MFMA16(kf1, qf1, z);
            bf16x8 aA, aB, vf;
            if (k32 + 31 <= q0w) {                  // full pair, no masking
#pragma unroll
                for (int r = 0; r < 4; ++r) {
                    aA[r] = bftrunc(exp2_fast(s0[r]));
                    aA[4 + r] = bftrunc(exp2_fast(s1[r]));
                    aB[r] = bftrunc(exp2_fast(s2[r]));
                    aB[4 + r] = bftrunc(exp2_fast(s3[r]));
                    vf[r] = v0[r];
                    vf[4 + r] = v1[r];
                }
            } else {                                // causal boundary: mask
                int qa = q0w + c, qb = q0w + 16 + c;
                int ka = k32 + 4 * g, kb = k32 + 16 + 4 * g;
#pragma unroll
                for (int r = 0; r < 4; ++r) {
                    aA[r] = (ka + r <= qa) ? bftrunc(exp2_fast(s0[r])) : (short)0;
                    aA[4 + r] = (kb + r <= qa) ? bftrunc(exp2_fast(s1[r])) : (short)0;
                    aB[r] = (ka + r <= qb) ? bftrunc(exp2_fast(s2[r])) : (short)0;
                    aB[4 + r] = (kb + r <= qb) ? bftrunc(exp2_fast(s3[r])) : (short)0;
                    vf[r] = v0[r];
                    vf[4 + r] = v1[r];
                }
            }
            acc0 = MFMA16(aA, vf, acc0);
            acc1 = MFMA16(aB, vf, acc1);
        }
        __syncthreads();
    }
#undef STAGE

    // combine halves: h=1 waves dump partials to LDS, h=0 waves add and store.
    float* Of = (float*)&Kt[0][0];          // 8 KB, staging done
    if (h == 1) {
#pragma unroll
        for (int r = 0; r < 4; ++r) {
            Of[r * 256 + s * 64 + lane] = acc0[r];
            Of[(4 + r) * 256 + s * 64 + lane] = acc1[r];
        }
    }
    __syncthreads();
    if (h == 0) {
#pragma unroll
        for (int r = 0; r < 4; ++r) {
            acc0[r] += Of[r * 256 + s * 64 + lane];
            acc1[r] += Of[(4 + r) * 256 + s * 64 + lane];
        }
#pragma unroll
        for (int r = 0; r < 4; ++r) {
            AObf[(size_t)(b * T_SEQ + q0w + 4 * g + r) * DMODEL + h2 * EHEAD + c] = f2bf(acc0[r]);
            AObf[(size_t)(b * T_SEQ + q0w + 16 + 4 * g + r) * DMODEL + h2 * EHEAD + c] = f2bf(acc1[r]);
        }
    }
}

// ---------------------------------------------------------------------------
// K4: fused FF: out = relu(AO@W1+b1)@W2 + b2 + xpe.
// Grid 256 blocks x 256 thr; block owns 32 rows (2 chunks of 16), weights
// loaded into registers ONCE and reused across chunks (halves L2 W-traffic).
// Phase 1: wave w computes F cols [w*128,+128) for both chunks -> LDS
// (32 x 516 padded). Phase 2: wave w computes out cols [w*32,+32).
// ---------------------------------------------------------------------------
__global__ __launch_bounds__(256) void k_ff(const short* __restrict__ AObf,
                                            const short* __restrict__ W1t,
                                            const float* __restrict__ b1,
                                            const short* __restrict__ W2t,
                                            const float* __restrict__ b2,
                                            const float* __restrict__ xpe,
                                            float* __restrict__ out) {
    __shared__ __align__(16) short Fl[32][516];
    int w = threadIdx.x >> 6, lane = threadIdx.x & 63;
    int g = lane >> 4, c = lane & 15;
    int row0 = blockIdx.x * 32;

    // ---- phase 1: F[r][w*128 + n] = relu(AO @ W1 + b1), 2 chunks ----
    {
        bf16x8 wf[8][4];
#pragma unroll
        for (int nt = 0; nt < 8; ++nt)
#pragma unroll
            for (int kk = 0; kk < 4; ++kk)
                wf[nt][kk] = *(const bf16x8*)(W1t + (w * 128 + nt * 16 + c) * 128 + kk * 32 + 8 * g);

#pragma unroll
        for (int ch = 0; ch < 2; ++ch) {
            int rbase = row0 + ch * 16;
            bf16x8 af[4];
#pragma unroll
            for (int kk = 0; kk < 4; ++kk)
                af[kk] = *(const bf16x8*)(AObf + (size_t)(rbase + c) * 128 + kk * 32 + 8 * g);

            f32x4 acc[8];
#pragma unroll
            for (int nt = 0; nt < 8; ++nt) acc[nt] = (f32x4){0.f, 0.f, 0.f, 0.f};
#pragma unroll
            for (int kk = 0; kk < 4; ++kk)
#pragma unroll
                for (int nt = 0; nt < 8; ++nt)
                    acc[nt] = MFMA16(af[kk], wf[nt][kk], acc[nt]);

#pragma unroll
            for (int nt = 0; nt < 8; ++nt) {
                int col = w * 128 + nt * 16 + c;
                float bb = b1[col];
#pragma unroll
                for (int r = 0; r < 4; ++r)
                    Fl[ch * 16 + 4 * g + r][col] = f2bf(fmaxf(acc[nt][r] + bb, 0.f));
            }
        }
    }
    __syncthreads();

    // ---- phase 2: out cols [w*32, +32) = F @ W2 + b2 + xpe, 2 chunks ----
    bf16x8 wf2[2][16];
#pragma unroll
    for (int nt = 0; nt < 2; ++nt)
#pragma unroll
        for (int kk = 0; kk < 16; ++kk)
            wf2[nt][kk] = *(const bf16x8*)(W2t + (w * 32 + nt * 16 + c) * 512 + kk * 32 + 8 * g);

#pragma unroll
    for (int ch = 0; ch < 2; ++ch) {
        int rbase = row0 + ch * 16;
        f32x4 acc2[2];
        acc2[0] = (f32x4){0.f, 0.f, 0.f, 0.f};
        acc2[1] = (f32x4){0.f, 0.f, 0.f, 0.f};
#pragma unroll
        for (int kk = 0; kk < 16; ++kk) {
            bf16x8 a = *(const bf16x8*)(&Fl[ch * 16 + c][kk * 32 + 8 * g]);
            acc2[0] = MFMA16(a, wf2[0][kk], acc2[0]);
            acc2[1] = MFMA16(a, wf2[1][kk], acc2[1]);
        }
#pragma unroll
        for (int nt = 0; nt < 2; ++nt) {
            int col = w * 32 + nt * 16 + c;
            float bb = b2[col];
#pragma unroll
            for (int r = 0; r < 4; ++r) {
                size_t o = (size_t)(rbase + 4 * g + r) * DMODEL + col;
                out[o] = acc2[nt][r] + bb + xpe[o];
            }
        }
    }
}

// ---------------------------------------------------------------------------
extern "C" void kernel_launch(void* const* d_in, const int* in_sizes, int n_in,
                              void* d_out, int out_size, void* d_ws, size_t ws_size,
                              hipStream_t stream) {
    const float* x  = (const float*)d_in[0];
    const float* WQ = (const float*)d_in[1];
    const float* WK = (const float*)d_in[2];
    const float* WV = (const float*)d_in[3];
    const float* W1 = (const float*)d_in[4];
    const float* b1 = (const float*)d_in[5];
    const float* W2 = (const float*)d_in[6];
    const float* b2 = (const float*)d_in[7];
    float* out = (float*)d_out;

    const size_t NTD = (size_t)BATCH * T_SEQ * DMODEL;   // 1048576
    float* xpe   = (float*)d_ws;
    short* Qh    = (short*)(xpe + NTD);
    short* Kh    = Qh + NTD;
    short* Vs    = Kh + NTD;
    short* AObf  = Vs + NTD;
    short* W1t   = AObf + NTD;
    short* W2t   = W1t + 65536;

    k_qkv<<<dim3(128, 4), dim3(256), 0, stream>>>(x, WQ, WK, WV, W1, W2,
                                                  xpe, Qh, Kh, Vs, W1t, W2t);

    k_csum<<<dim3(512), dim3(512), 0, stream>>>(Qh, Kh, Vs);

    k_attn<<<dim3(512), dim3(512), 0, stream>>>(Qh, Kh, Vs, AObf);

    k_ff<<<dim3(256), dim3(256), 0, stream>>>(AObf, W1t, b1, W2t, b2, xpe, out);
}

// Round 14
// 55.314 us; speedup vs baseline: 1.6033x; 1.0762x over previous
//
#include <hip/hip_runtime.h>
#include <math.h>
#include <stdint.h>

#define T_SEQ 2048
#define BATCH 4
#define DMODEL 128
#define DFF 512
#define NHEAD 8
#define EHEAD 16

#define QSCALE (0.022097086912079608f * 1.4426950408889634f)   // rsqrt(T) * log2(e)

typedef __attribute__((ext_vector_type(8))) short bf16x8;
typedef __attribute__((ext_vector_type(4))) short bf16x4;
typedef __attribute__((ext_vector_type(4))) float f32x4;

__device__ __forceinline__ short f2bf(float f) {            // RNE
    uint32_t u = __float_as_uint(f);
    u = u + 0x7FFF + ((u >> 16) & 1);
    return (short)(u >> 16);
}
__device__ __forceinline__ short bftrunc(float f) {         // truncate (cheap)
    return (short)(__float_as_uint(f) >> 16);
}
__device__ __forceinline__ float bf2f(short s) {
    return __uint_as_float(((uint32_t)(unsigned short)s) << 16);
}
__device__ __forceinline__ float exp2_fast(float x) {       // raw v_exp_f32
#if __has_builtin(__builtin_amdgcn_exp2f)
    return __builtin_amdgcn_exp2f(x);
#else
    float r; asm("v_exp_f32 %0, %1" : "=v"(r) : "v"(x)); return r;
#endif
}

#define MFMA16(A, B, C) __builtin_amdgcn_mfma_f32_16x16x32_bf16(A, B, C, 0, 0, 0)

__device__ __forceinline__ void gload16(const void* g, void* l) {
    __builtin_amdgcn_global_load_lds(
        (const __attribute__((address_space(1))) void*)g,
        (__attribute__((address_space(3))) void*)l, 16, 0, 0);
}

// quad-complementary rank mapping for 1024 blocks, 4 co-resident per CU:
// IDs {c, c+256, c+512, c+768} -> ranks {c, 511-c, 512+c, 1023-c}, so the 4
// blocks sharing a CU have near-constant total triangular work.
__device__ __forceinline__ int quad_rank(int id) {
    int group = id >> 8, pos = id & 255;
    return (group & 1) ? (((group + 1) << 8) - 1 - pos) : ((group << 8) + pos);
}

// ---------------------------------------------------------------------------
// K1: fused prep + QKV projection. Grid (128, 4), block 256.
// z<3: block owns 64 rows; computes x+PE inline (A-fragments in registers,
//      z=0 also writes fp32 xpe for the residual), converts its W to a
//      bf16-transposed LDS tile (pad-136 rows, conflict-free b128 reads),
//      then MFMA GEMM. z=0: Qh *= QSCALE; z=1: Kh; z=2: Vs[hb][e][T].
// z=3: 128 trivial blocks convert W1->W1t, W2->W2t for k_ff (consumed by a
//      LATER launch only -- no same-launch dependency).
// ---------------------------------------------------------------------------
#define WP 136      // padded LDS row stride (shorts): 272 B, 16B-aligned
__global__ __launch_bounds__(256) void k_qkv(const float* __restrict__ x,
                                             const float* __restrict__ WQ,
                                             const float* __restrict__ WK,
                                             const float* __restrict__ WV,
                                             const float* __restrict__ W1,
                                             const float* __restrict__ W2,
                                             float* __restrict__ xpe,
                                             short* __restrict__ Qh,
                                             short* __restrict__ Kh,
                                             short* __restrict__ Vs,
                                             short* __restrict__ W1t,
                                             short* __restrict__ W2t) {
    __shared__ __align__(16) short Wlds[128 * WP];
    int z = blockIdx.y;
    int tid = threadIdx.x;

    if (z == 3) {                           // W1/W2 -> bf16 transposed
        int base = (int)blockIdx.x * 256 + tid;      // 0..32767
#pragma unroll
        for (int i = 0; i < 2; ++i) {
            int o = base + i * 32768;                // W1t: 65536 = n*128+k
            int n = o >> 7, k = o & 127;
            W1t[o] = f2bf(W1[k * 512 + n]);
        }
#pragma unroll
        for (int i = 0; i < 2; ++i) {
            int o = base + i * 32768;                // W2t: 65536 = n*512+k
            int n = o >> 9, k = o & 511;
            W2t[o] = f2bf(W2[k * 128 + n]);
        }
        return;
    }

    int wave = tid >> 6, lane = tid & 63;
    int g = lane >> 4, c = lane & 15;
    int row0 = blockIdx.x * 64 + wave * 16;
    int row = row0 + c;
    int tloc = row & (T_SEQ - 1);

    // ---- stage W^T (bf16) into LDS: thread owns k-row (tid&127), 64 n's ----
    {
        const float* Wsrc = (z == 0) ? WQ : (z == 1) ? WK : WV;
        int k = tid & 127, n0 = (tid >> 7) * 64;
        const float* src = Wsrc + k * 128 + n0;
#pragma unroll
        for (int j = 0; j < 64; j += 4) {
            float4 wv = *(const float4*)(src + j);
            Wlds[(n0 + j + 0) * WP + k] = f2bf(wv.x);
            Wlds[(n0 + j + 1) * WP + k] = f2bf(wv.y);
            Wlds[(n0 + j + 2) * WP + k] = f2bf(wv.z);
            Wlds[(n0 + j + 3) * WP + k] = f2bf(wv.w);
        }
    }

    // ---- A-fragments: af = bf16(x + PE); z=0 writes fp32 xpe ----
    bf16x8 af[4];
#pragma unroll
    for (int kk = 0; kk < 4; ++kk) {
        int d0 = kk * 32 + 8 * g;
        const float* xb = x + (size_t)row * 128 + d0;
        float4 xa = *(const float4*)(xb);
        float4 xc = *(const float4*)(xb + 4);
        float vv[8] = {xa.x, xa.y, xa.z, xa.w, xc.x, xc.y, xc.z, xc.w};
#pragma unroll
        for (int p = 0; p < 4; ++p) {
            int d = d0 + 2 * p;
            float dv = __expf(-(float)d * (9.210340371976184f / 128.0f));
            float ang = (float)tloc * dv;
            vv[2 * p] += __sinf(ang);
            vv[2 * p + 1] += __cosf(ang);
        }
        if (z == 0) {
            float* xo = xpe + (size_t)row * 128 + d0;
            *(float4*)(xo) = make_float4(vv[0], vv[1], vv[2], vv[3]);
            *(float4*)(xo + 4) = make_float4(vv[4], vv[5], vv[6], vv[7]);
        }
#pragma unroll
        for (int j = 0; j < 8; ++j) af[kk][j] = f2bf(vv[j]);
    }
    __syncthreads();

    // ---- W fragments from LDS + MFMA ----
    bf16x8 wf[8][4];
#pragma unroll
    for (int nt = 0; nt < 8; ++nt)
#pragma unroll
        for (int kk = 0; kk < 4; ++kk)
            wf[nt][kk] = *(const bf16x8*)(&Wlds[(nt * 16 + c) * WP + kk * 32 + 8 * g]);

    f32x4 acc[8];
#pragma unroll
    for (int nt = 0; nt < 8; ++nt) acc[nt] = (f32x4){0.f, 0.f, 0.f, 0.f};
#pragma unroll
    for (int kk = 0; kk < 4; ++kk)
#pragma unroll
        for (int nt = 0; nt < 8; ++nt)
            acc[nt] = MFMA16(af[kk], wf[nt][kk], acc[nt]);

    int b = row0 >> 11;
    int t0 = (row0 & (T_SEQ - 1)) + 4 * g;
    if (z < 2) {
        short* dst = (z == 0) ? Qh : Kh;
        float sc = (z == 0) ? QSCALE : 1.0f;
#pragma unroll
        for (int nt = 0; nt < 8; ++nt) {
            int hb = nt * 4 + b;
#pragma unroll
            for (int r = 0; r < 4; ++r)
                dst[(size_t)(hb * T_SEQ + t0 + r) * 16 + c] = f2bf(acc[nt][r] * sc);
        }
    } else {
#pragma unroll
        for (int nt = 0; nt < 8; ++nt) {
            int hb = nt * 4 + b;
            bf16x4 v;
#pragma unroll
            for (int r = 0; r < 4; ++r) v[r] = f2bf(acc[nt][r]);
            *(bf16x4*)(Vs + (size_t)(hb * 16 + c) * T_SEQ + t0) = v;
        }
    }
}
#undef WP

// ---------------------------------------------------------------------------
// K2: column softmax denominators + V scaling. 256-thr blocks (4 waves),
// grid 1024 (4 blocks/CU), quad_rank balanced. rank: kc = rank>>5 (64-col
// chunk, 0 = longest), hb = rank&31. Wave w = (strip s=w&1 -> 32 cols, half
// h=w>>1 -> q-slots {4h..4h+3} of each staged 256-q tile). Partial sums
// combined via LDS; block scales Vs columns [kc*64, +64) at the end.
// ---------------------------------------------------------------------------
__global__ __launch_bounds__(256, 4) void k_csum(const short* __restrict__ Qh,
                                                 const short* __restrict__ Kh,
                                                 short* __restrict__ Vs) {
    __shared__ __align__(16) short Qt[2][4096];
    __shared__ float csLds[4][32];
    __shared__ float invl[64];
    const bf16x8 zz = {0, 0, 0, 0, 0, 0, 0, 0};
    const f32x4 z = {0.f, 0.f, 0.f, 0.f};

    int rank = quad_rank((int)blockIdx.x);
    int kc = rank >> 5, hb = rank & 31;
    int tid = threadIdx.x;
    int wave = tid >> 6, lane = tid & 63;
    int g = lane >> 4, c = lane & 15;
    int s = wave & 1, h = wave >> 1;
    int kw = kc * 64 + s * 32;
    const size_t hbT = (size_t)hb * T_SEQ;
    const short* Qg = Qh + hbT * 16;

    bf16x8 kfA = zz, kfB = zz;
    if (g < 2) {
        kfA = *(const bf16x8*)(Kh + (hbT + kw + c) * 16 + 8 * g);
        kfB = *(const bf16x8*)(Kh + (hbT + kw + 16 + c) * 16 + 8 * g);
    }

#define QSTAGE(bf, tq)                                                       \
    do {                                                                     \
        const short* src = Qg + (size_t)(tq) * 4096;                         \
        gload16(src + tid * 8, &Qt[bf][tid * 8]);                            \
        gload16(src + 2048 + tid * 8, &Qt[bf][2048 + tid * 8]);              \
    } while (0)

    int tstart = kc >> 2;                   // first 256-q tile with q >= kc*64
    QSTAGE(0, tstart);
    __syncthreads();

    float csA = 0.f, csB = 0.f;
    for (int t = tstart; t < 8; ++t) {
        int buf = (t - tstart) & 1;
        if (t + 1 < 8) QSTAGE(buf ^ 1, t + 1);
        const short* Qtb = &Qt[buf][0];
#pragma unroll
        for (int sj = 0; sj < 4; ++sj) {
            int ss = 4 * h + sj;
            int q32 = t * 256 + ss * 32;
            if (q32 + 31 < kw) continue;            // fully above diagonal
            bf16x8 qfa = zz, qfb = zz;
            if (g < 2) {
                qfa = *(const bf16x8*)(Qtb + (ss * 32 + c) * 16 + g * 8);
                qfb = *(const bf16x8*)(Qtb + (ss * 32 + 16 + c) * 16 + g * 8);
            }
            f32x4 sA1 = MFMA16(qfa, kfA, z);
            f32x4 sB1 = MFMA16(qfa, kfB, z);
            f32x4 sA2 = MFMA16(qfb, kfA, z);
            f32x4 sB2 = MFMA16(qfb, kfB, z);
            if (q32 >= kw + 32) {                   // fully below diagonal
#pragma unroll
                for (int r = 0; r < 4; ++r) {
                    csA += exp2_fast(sA1[r]) + exp2_fast(sA2[r]);
                    csB += exp2_fast(sB1[r]) + exp2_fast(sB2[r]);
                }
            } else {                                // diagonal region: mask
                int kA = kw + c, kB = kw + 16 + c;
#pragma unroll
                for (int r = 0; r < 4; ++r) {
                    int qa = q32 + 4 * g + r, qb = q32 + 16 + 4 * g + r;
                    csA += (qa >= kA) ? exp2_fast(sA1[r]) : 0.f;
                    csA += (qb >= kA) ? exp2_fast(sA2[r]) : 0.f;
                    csB += (qa >= kB) ? exp2_fast(sB1[r]) : 0.f;
                    csB += (qb >= kB) ? exp2_fast(sB2[r]) : 0.f;
                }
            }
        }
        __syncthreads();
    }
#undef QSTAGE

    csA += __shfl_xor(csA, 16);
    csA += __shfl_xor(csA, 32);
    csB += __shfl_xor(csB, 16);
    csB += __shfl_xor(csB, 32);
    if (lane < 32) csLds[wave][lane] = (lane < 16) ? csA : csB;
    __syncthreads();
    if (tid < 64) {                         // strip = tid>>5, col-in-strip = tid&31
        int st = tid >> 5, col = tid & 31;
        invl[tid] = 1.0f / (csLds[st][col] + csLds[st + 2][col]);
    }
    __syncthreads();
    if (tid < 128) {                        // scale V cols [kc*64, +64)
        int e = tid >> 3, kcol = (tid & 7) * 8;
        size_t vo = (size_t)(hb * 16 + e) * T_SEQ + kc * 64 + kcol;
        bf16x8 v = *(bf16x8*)(Vs + vo);
        bf16x8 o;
#pragma unroll
        for (int j = 0; j < 8; ++j) o[j] = f2bf(bf2f(v[j]) * invl[kcol + j]);
        *(bf16x8*)(Vs + vo) = o;
    }
}

// ---------------------------------------------------------------------------
// K3: attention output. 256-thr blocks (4 waves), grid 1024 (4 blocks/CU),
// quad_rank balanced. rank: qn = 31-(rank>>5) (rank 0 = longest), hb = rank&31.
// Block owns a 64-q chunk; wave w = (strip s=w&1 -> q0w = qn*64+s*32, half
// h=w>>1 -> k-slots {4h..4h+3} of each staged 256-k tile). K linear + V
// e-major XOR-swizzled tiles double-buffered via global_load_lds. Partial O
// combined via LDS. O[q] = sum_{k<=q} exp2(S') * Vs (V pre-scaled).
// ---------------------------------------------------------------------------
__global__ __launch_bounds__(256, 4) void k_attn(const short* __restrict__ Qh,
                                                 const short* __restrict__ Kh,
                                                 const short* __restrict__ Vs,
                                                 short* __restrict__ AObf) {
    __shared__ __align__(16) short Kt[2][4096];
    __shared__ __align__(16) short Vt[2][4096];
    const bf16x8 zz = {0, 0, 0, 0, 0, 0, 0, 0};
    const f32x4 z = {0.f, 0.f, 0.f, 0.f};

    int rank = quad_rank((int)blockIdx.x);
    int qn = 31 - (rank >> 5), hb = rank & 31;
    int h2 = hb >> 2, b = hb & 3;
    int tid = threadIdx.x;
    int wave = tid >> 6, lane = tid & 63;
    int g = lane >> 4, c = lane & 15;
    int s = wave & 1, h = wave >> 1;
    int q0w = qn * 64 + s * 32;
    const size_t hbT = (size_t)hb * T_SEQ;
    const short* Kg = Kh + hbT * 16;
    const short* Vg = Vs + (size_t)hb * 16 * T_SEQ;

    bf16x8 qf0 = zz, qf1 = zz;
    if (g < 2) {
        qf0 = *(const bf16x8*)(Qh + (hbT + q0w + c) * 16 + 8 * g);
        qf1 = *(const bf16x8*)(Qh + (hbT + q0w + 16 + c) * 16 + 8 * g);
    }

    int nT = (qn >> 2) + 1;                 // 256-k tiles this block touches

#define STAGE(bf, kt)                                                        \
    do {                                                                     \
        int k0s = (kt) * 256;                                                \
        gload16(Kg + (size_t)k0s * 16 + tid * 8, &Kt[bf][tid * 8]);          \
        gload16(Kg + (size_t)k0s * 16 + 2048 + tid * 8,                      \
                &Kt[bf][2048 + tid * 8]);                                    \
        int e0 = tid >> 5, j0 = (tid & 31) ^ (e0 & 7);                       \
        gload16(Vg + (size_t)e0 * T_SEQ + k0s + j0 * 8, &Vt[bf][tid * 8]);   \
        int s1_ = tid + 256;                                                 \
        int e1 = s1_ >> 5, j1 = (s1_ & 31) ^ (e1 & 7);                       \
        gload16(Vg + (size_t)e1 * T_SEQ + k0s + j1 * 8,                      \
                &Vt[bf][2048 + tid * 8]);                                    \
    } while (0)

    STAGE(0, 0);
    __syncthreads();

    f32x4 acc0 = z, acc1 = z;
    for (int t = 0; t < nT; ++t) {
        int buf = t & 1;
        if (t + 1 < nT) STAGE(buf ^ 1, t + 1);
        const short* Ktb = &Kt[buf][0];
        const short* Vtb = &Vt[buf][0];
#pragma unroll
        for (int sj = 0; sj < 4; ++sj) {
            int ss = 4 * h + sj;
            int k32 = t * 256 + ss * 32;
            if (k32 > q0w + 31) continue;           // above causal range
            bf16x8 kf0 = zz, kf1 = zz;
            if (g < 2) {
                kf0 = *(const bf16x8*)(Ktb + (ss * 32 + c) * 16 + g * 8);
                kf1 = *(const bf16x8*)(Ktb + (ss * 32 + 16 + c) * 16 + g * 8);
            }
            int ja = ss * 4 + (g >> 1);             // granule in 32-granule row
            const short* vrow = Vtb + c * 256 + ((g & 1) << 2);
            bf16x4 v0 = *(const bf16x4*)(vrow + ((ja ^ (c & 7)) << 3));
            bf16x4 v1 = *(const bf16x4*)(vrow + (((ja + 2) ^ (c & 7)) << 3));
            f32x4 s0 = MFMA16(kf0, qf0, z);
            f32x4 s1 = MFMA16(kf1, qf0, z);
            f32x4 s2 = MFMA16(kf0, qf1, z);
            f32x4 s3 = MFMA16(kf1, qf1, z);
            bf16x8 aA, aB, vf;
            if (k32 + 31 <= q0w) {                  // full pair, no masking
#pragma unroll
                for (int r = 0; r < 4; ++r) {
                    aA[r] = bftrunc(exp2_fast(s0[r]));
                    aA[4 + r] = bftrunc(exp2_fast(s1[r]));
                    aB[r] = bftrunc(exp2_fast(s2[r]));
                    aB[4 + r] = bftrunc(exp2_fast(s3[r]));
                    vf[r] = v0[r];
                    vf[4 + r] = v1[r];
                }
            } else {                                // causal boundary: mask
                int qa = q0w + c, qb = q0w + 16 + c;
                int ka = k32 + 4 * g, kb = k32 + 16 + 4 * g;
#pragma unroll
                for (int r = 0; r < 4; ++r) {
                    aA[r] = (ka + r <= qa) ? bftrunc(exp2_fast(s0[r])) : (short)0;
                    aA[4 + r] = (kb + r <= qa) ? bftrunc(exp2_fast(s1[r])) : (short)0;
                    aB[r] = (ka + r <= qb) ? bftrunc(exp2_fast(s2[r])) : (short)0;
                    aB[4 + r] = (kb + r <= qb) ? bftrunc(exp2_fast(s3[r])) : (short)0;
                    vf[r] = v0[r];
                    vf[4 + r] = v1[r];
                }
            }
            acc0 = MFMA16(aA, vf, acc0);
            acc1 = MFMA16(aB, vf, acc1);
        }
        __syncthreads();
    }
#undef STAGE

    // combine halves: h=1 waves dump partials to LDS, h=0 waves add and store.
    float* Of = (float*)&Kt[0][0];          // 4 KB needed, staging done
    if (h == 1) {
#pragma unroll
        for (int r = 0; r < 4; ++r) {
            Of[r * 128 + s * 64 + lane] = acc0[r];
            Of[(4 + r) * 128 + s * 64 + lane] = acc1[r];
        }
    }
    __syncthreads();
    if (h == 0) {
#pragma unroll
        for (int r = 0; r < 4; ++r) {
            acc0[r] += Of[r * 128 + s * 64 + lane];
            acc1[r] += Of[(4 + r) * 128 + s * 64 + lane];
        }
#pragma unroll
        for (int r = 0; r < 4; ++r) {
            AObf[(size_t)(b * T_SEQ + q0w + 4 * g + r) * DMODEL + h2 * EHEAD + c] = f2bf(acc0[r]);
            AObf[(size_t)(b * T_SEQ + q0w + 16 + 4 * g + r) * DMODEL + h2 * EHEAD + c] = f2bf(acc1[r]);
        }
    }
}

// ---------------------------------------------------------------------------
// K4: fused FF: out = relu(AO@W1+b1)@W2 + b2 + xpe.
// Grid 256 blocks x 256 thr; block owns 32 rows (2 chunks of 16), weights
// loaded into registers ONCE and reused across chunks (halves L2 W-traffic).
// Phase 1: wave w computes F cols [w*128,+128) for both chunks -> LDS
// (32 x 516 padded). Phase 2: wave w computes out cols [w*32,+32).
// ---------------------------------------------------------------------------
__global__ __launch_bounds__(256) void k_ff(const short* __restrict__ AObf,
                                            const short* __restrict__ W1t,
                                            const float* __restrict__ b1,
                                            const short* __restrict__ W2t,
                                            const float* __restrict__ b2,
                                            const float* __restrict__ xpe,
                                            float* __restrict__ out) {
    __shared__ __align__(16) short Fl[32][516];
    int w = threadIdx.x >> 6, lane = threadIdx.x & 63;
    int g = lane >> 4, c = lane & 15;
    int row0 = blockIdx.x * 32;

    // ---- phase 1: F[r][w*128 + n] = relu(AO @ W1 + b1), 2 chunks ----
    {
        bf16x8 wf[8][4];
#pragma unroll
        for (int nt = 0; nt < 8; ++nt)
#pragma unroll
            for (int kk = 0; kk < 4; ++kk)
                wf[nt][kk] = *(const bf16x8*)(W1t + (w * 128 + nt * 16 + c) * 128 + kk * 32 + 8 * g);

#pragma unroll
        for (int ch = 0; ch < 2; ++ch) {
            int rbase = row0 + ch * 16;
            bf16x8 af[4];
#pragma unroll
            for (int kk = 0; kk < 4; ++kk)
                af[kk] = *(const bf16x8*)(AObf + (size_t)(rbase + c) * 128 + kk * 32 + 8 * g);

            f32x4 acc[8];
#pragma unroll
            for (int nt = 0; nt < 8; ++nt) acc[nt] = (f32x4){0.f, 0.f, 0.f, 0.f};
#pragma unroll
            for (int kk = 0; kk < 4; ++kk)
#pragma unroll
                for (int nt = 0; nt < 8; ++nt)
                    acc[nt] = MFMA16(af[kk], wf[nt][kk], acc[nt]);

#pragma unroll
            for (int nt = 0; nt < 8; ++nt) {
                int col = w * 128 + nt * 16 + c;
                float bb = b1[col];
#pragma unroll
                for (int r = 0; r < 4; ++r)
                    Fl[ch * 16 + 4 * g + r][col] = f2bf(fmaxf(acc[nt][r] + bb, 0.f));
            }
        }
    }
    __syncthreads();

    // ---- phase 2: out cols [w*32, +32) = F @ W2 + b2 + xpe, 2 chunks ----
    bf16x8 wf2[2][16];
#pragma unroll
    for (int nt = 0; nt < 2; ++nt)
#pragma unroll
        for (int kk = 0; kk < 16; ++kk)
            wf2[nt][kk] = *(const bf16x8*)(W2t + (w * 32 + nt * 16 + c) * 512 + kk * 32 + 8 * g);

#pragma unroll
    for (int ch = 0; ch < 2; ++ch) {
        int rbase = row0 + ch * 16;
        f32x4 acc2[2];
        acc2[0] = (f32x4){0.f, 0.f, 0.f, 0.f};
        acc2[1] = (f32x4){0.f, 0.f, 0.f, 0.f};
#pragma unroll
        for (int kk = 0; kk < 16; ++kk) {
            bf16x8 a = *(const bf16x8*)(&Fl[ch * 16 + c][kk * 32 + 8 * g]);
            acc2[0] = MFMA16(a, wf2[0][kk], acc2[0]);
            acc2[1] = MFMA16(a, wf2[1][kk], acc2[1]);
        }
#pragma unroll
        for (int nt = 0; nt < 2; ++nt) {
            int col = w * 32 + nt * 16 + c;
            float bb = b2[col];
#pragma unroll
            for (int r = 0; r < 4; ++r) {
                size_t o = (size_t)(rbase + 4 * g + r) * DMODEL + col;
                out[o] = acc2[nt][r] + bb + xpe[o];
            }
        }
    }
}

// ---------------------------------------------------------------------------
extern "C" void kernel_launch(void* const* d_in, const int* in_sizes, int n_in,
                              void* d_out, int out_size, void* d_ws, size_t ws_size,
                              hipStream_t stream) {
    const float* x  = (const float*)d_in[0];
    const float* WQ = (const float*)d_in[1];
    const float* WK = (const float*)d_in[2];
    const float* WV = (const float*)d_in[3];
    const float* W1 = (const float*)d_in[4];
    const float* b1 = (const float*)d_in[5];
    const float* W2 = (const float*)d_in[6];
    const float* b2 = (const float*)d_in[7];
    float* out = (float*)d_out;

    const size_t NTD = (size_t)BATCH * T_SEQ * DMODEL;   // 1048576
    float* xpe   = (float*)d_ws;
    short* Qh    = (short*)(xpe + NTD);
    short* Kh    = Qh + NTD;
    short* Vs    = Kh + NTD;
    short* AObf  = Vs + NTD;
    short* W1t   = AObf + NTD;
    short* W2t   = W1t + 65536;

    k_qkv<<<dim3(128, 4), dim3(256), 0, stream>>>(x, WQ, WK, WV, W1, W2,
                                                  xpe, Qh, Kh, Vs, W1t, W2t);

    k_csum<<<dim3(1024), dim3(256), 0, stream>>>(Qh, Kh, Vs);

    k_attn<<<dim3(1024), dim3(256), 0, stream>>>(Qh, Kh, Vs, AObf);

    k_ff<<<dim3(256), dim3(256), 0, stream>>>(AObf, W1t, b1, W2t, b2, xpe, out);
}

// Round 17
// 54.851 us; speedup vs baseline: 1.6168x; 1.0084x over previous
//
#include <hip/hip_runtime.h>
#include <math.h>
#include <stdint.h>

#define T_SEQ 2048
#define BATCH 4
#define DMODEL 128
#define DFF 512
#define NHEAD 8
#define EHEAD 16

#define QSCALE (0.022097086912079608f * 1.4426950408889634f)   // rsqrt(T) * log2(e)

typedef __attribute__((ext_vector_type(8))) short bf16x8;
typedef __attribute__((ext_vector_type(4))) short bf16x4;
typedef __attribute__((ext_vector_type(4))) float f32x4;

__device__ __forceinline__ short f2bf(float f) {            // RNE
    uint32_t u = __float_as_uint(f);
    u = u + 0x7FFF + ((u >> 16) & 1);
    return (short)(u >> 16);
}
__device__ __forceinline__ short bftrunc(float f) {         // truncate (cheap)
    return (short)(__float_as_uint(f) >> 16);
}
__device__ __forceinline__ float bf2f(short s) {
    return __uint_as_float(((uint32_t)(unsigned short)s) << 16);
}
__device__ __forceinline__ float exp2_fast(float x) {       // raw v_exp_f32
#if __has_builtin(__builtin_amdgcn_exp2f)
    return __builtin_amdgcn_exp2f(x);
#else
    float r; asm("v_exp_f32 %0, %1" : "=v"(r) : "v"(x)); return r;
#endif
}

#define MFMA16(A, B, C) __builtin_amdgcn_mfma_f32_16x16x32_bf16(A, B, C, 0, 0, 0)

__device__ __forceinline__ void gload16(const void* g, void* l) {
    __builtin_amdgcn_global_load_lds(
        (const __attribute__((address_space(1))) void*)g,
        (__attribute__((address_space(3))) void*)l, 16, 0, 0);
}

// quad-complementary rank mapping for 1024 blocks, 4 co-resident per CU:
// IDs {c, c+256, c+512, c+768} -> ranks {c, 511-c, 512+c, 1023-c}, so the 4
// blocks sharing a CU have near-constant total triangular work.
__device__ __forceinline__ int quad_rank(int id) {
    int group = id >> 8, pos = id & 255;
    return (group & 1) ? (((group + 1) << 8) - 1 - pos) : ((group << 8) + pos);
}

// ---------------------------------------------------------------------------
// K1: fused prep + QKV projection. Grid (128, 4), block 256.
// z<3: block owns 64 rows; computes x+PE inline (A-fragments in registers,
//      z=0 also writes fp32 xpe for the residual), converts its W to a
//      bf16-transposed LDS tile (pad-136 rows, conflict-free b128 reads),
//      then MFMA GEMM. z=0: Qh *= QSCALE; z=1: Kh; z=2: Vs[hb][e][T].
// z=3: 128 trivial blocks convert W1->W1t, W2->W2t for k_ff (consumed by a
//      LATER launch only -- no same-launch dependency).
// ---------------------------------------------------------------------------
#define WP 136      // padded LDS row stride (shorts): 272 B, 16B-aligned
__global__ __launch_bounds__(256) void k_qkv(const float* __restrict__ x,
                                             const float* __restrict__ WQ,
                                             const float* __restrict__ WK,
                                             const float* __restrict__ WV,
                                             const float* __restrict__ W1,
                                             const float* __restrict__ W2,
                                             float* __restrict__ xpe,
                                             short* __restrict__ Qh,
                                             short* __restrict__ Kh,
                                             short* __restrict__ Vs,
                                             short* __restrict__ W1t,
                                             short* __restrict__ W2t) {
    __shared__ __align__(16) short Wlds[128 * WP];
    int z = blockIdx.y;
    int tid = threadIdx.x;

    if (z == 3) {                           // W1/W2 -> bf16 transposed
        int base = (int)blockIdx.x * 256 + tid;      // 0..32767
#pragma unroll
        for (int i = 0; i < 2; ++i) {
            int o = base + i * 32768;                // W1t: 65536 = n*128+k
            int n = o >> 7, k = o & 127;
            W1t[o] = f2bf(W1[k * 512 + n]);
        }
#pragma unroll
        for (int i = 0; i < 2; ++i) {
            int o = base + i * 32768;                // W2t: 65536 = n*512+k
            int n = o >> 9, k = o & 511;
            W2t[o] = f2bf(W2[k * 128 + n]);
        }
        return;
    }

    int wave = tid >> 6, lane = tid & 63;
    int g = lane >> 4, c = lane & 15;
    int row0 = blockIdx.x * 64 + wave * 16;
    int row = row0 + c;
    int tloc = row & (T_SEQ - 1);

    // ---- stage W^T (bf16) into LDS: thread owns k-row (tid&127), 64 n's ----
    {
        const float* Wsrc = (z == 0) ? WQ : (z == 1) ? WK : WV;
        int k = tid & 127, n0 = (tid >> 7) * 64;
        const float* src = Wsrc + k * 128 + n0;
#pragma unroll
        for (int j = 0; j < 64; j += 4) {
            float4 wv = *(const float4*)(src + j);
            Wlds[(n0 + j + 0) * WP + k] = f2bf(wv.x);
            Wlds[(n0 + j + 1) * WP + k] = f2bf(wv.y);
            Wlds[(n0 + j + 2) * WP + k] = f2bf(wv.z);
            Wlds[(n0 + j + 3) * WP + k] = f2bf(wv.w);
        }
    }

    // ---- A-fragments: af = bf16(x + PE); z=0 writes fp32 xpe ----
    bf16x8 af[4];
#pragma unroll
    for (int kk = 0; kk < 4; ++kk) {
        int d0 = kk * 32 + 8 * g;
        const float* xb = x + (size_t)row * 128 + d0;
        float4 xa = *(const float4*)(xb);
        float4 xc = *(const float4*)(xb + 4);
        float vv[8] = {xa.x, xa.y, xa.z, xa.w, xc.x, xc.y, xc.z, xc.w};
#pragma unroll
        for (int p = 0; p < 4; ++p) {
            int d = d0 + 2 * p;
            float dv = __expf(-(float)d * (9.210340371976184f / 128.0f));
            float ang = (float)tloc * dv;
            vv[2 * p] += __sinf(ang);
            vv[2 * p + 1] += __cosf(ang);
        }
        if (z == 0) {
            float* xo = xpe + (size_t)row * 128 + d0;
            *(float4*)(xo) = make_float4(vv[0], vv[1], vv[2], vv[3]);
            *(float4*)(xo + 4) = make_float4(vv[4], vv[5], vv[6], vv[7]);
        }
#pragma unroll
        for (int j = 0; j < 8; ++j) af[kk][j] = f2bf(vv[j]);
    }
    __syncthreads();

    // ---- W fragments from LDS + MFMA ----
    bf16x8 wf[8][4];
#pragma unroll
    for (int nt = 0; nt < 8; ++nt)
#pragma unroll
        for (int kk = 0; kk < 4; ++kk)
            wf[nt][kk] = *(const bf16x8*)(&Wlds[(nt * 16 + c) * WP + kk * 32 + 8 * g]);

    f32x4 acc[8];
#pragma unroll
    for (int nt = 0; nt < 8; ++nt) acc[nt] = (f32x4){0.f, 0.f, 0.f, 0.f};
#pragma unroll
    for (int kk = 0; kk < 4; ++kk)
#pragma unroll
        for (int nt = 0; nt < 8; ++nt)
            acc[nt] = MFMA16(af[kk], wf[nt][kk], acc[nt]);

    int b = row0 >> 11;
    int t0 = (row0 & (T_SEQ - 1)) + 4 * g;
    if (z < 2) {
        short* dst = (z == 0) ? Qh : Kh;
        float sc = (z == 0) ? QSCALE : 1.0f;
#pragma unroll
        for (int nt = 0; nt < 8; ++nt) {
            int hb = nt * 4 + b;
#pragma unroll
            for (int r = 0; r < 4; ++r)
                dst[(size_t)(hb * T_SEQ + t0 + r) * 16 + c] = f2bf(acc[nt][r] * sc);
        }
    } else {
#pragma unroll
        for (int nt = 0; nt < 8; ++nt) {
            int hb = nt * 4 + b;
            bf16x4 v;
#pragma unroll
            for (int r = 0; r < 4; ++r) v[r] = f2bf(acc[nt][r]);
            *(bf16x4*)(Vs + (size_t)(hb * 16 + c) * T_SEQ + t0) = v;
        }
    }
}
#undef WP

// ---------------------------------------------------------------------------
// K2: column softmax denominators + V scaling. 256-thr blocks (4 waves),
// grid 1024 (4 blocks/CU), quad_rank balanced. rank: kc = rank>>5 (64-col
// chunk, 0 = longest), hb = rank&31. Wave w = (strip s=w&1 -> 32 cols, half
// h=w>>1 -> q-slots {4h..4h+3} of each staged 256-q tile). Partial sums
// combined via LDS; block scales Vs columns [kc*64, +64) at the end.
// ---------------------------------------------------------------------------
__global__ __launch_bounds__(256, 4) void k_csum(const short* __restrict__ Qh,
                                                 const short* __restrict__ Kh,
                                                 short* __restrict__ Vs) {
    __shared__ __align__(16) short Qt[2][4096];
    __shared__ float csLds[4][32];
    __shared__ float invl[64];
    const bf16x8 zz = {0, 0, 0, 0, 0, 0, 0, 0};
    const f32x4 z = {0.f, 0.f, 0.f, 0.f};

    int rank = quad_rank((int)blockIdx.x);
    int kc = rank >> 5, hb = rank & 31;
    int tid = threadIdx.x;
    int wave = tid >> 6, lane = tid & 63;
    int g = lane >> 4, c = lane & 15;
    int s = wave & 1, h = wave >> 1;
    int kw = kc * 64 + s * 32;
    const size_t hbT = (size_t)hb * T_SEQ;
    const short* Qg = Qh + hbT * 16;

    bf16x8 kfA = zz, kfB = zz;
    if (g < 2) {
        kfA = *(const bf16x8*)(Kh + (hbT + kw + c) * 16 + 8 * g);
        kfB = *(const bf16x8*)(Kh + (hbT + kw + 16 + c) * 16 + 8 * g);
    }

#define QSTAGE(bf, tq)                                                       \
    do {                                                                     \
        const short* src = Qg + (size_t)(tq) * 4096;                         \
        gload16(src + tid * 8, &Qt[bf][tid * 8]);                            \
        gload16(src + 2048 + tid * 8, &Qt[bf][2048 + tid * 8]);              \
    } while (0)

    int tstart = kc >> 2;                   // first 256-q tile with q >= kc*64
    QSTAGE(0, tstart);
    __syncthreads();

    float csA = 0.f, csB = 0.f;
    for (int t = tstart; t < 8; ++t) {
        int buf = (t - tstart) & 1;
        if (t + 1 < 8) QSTAGE(buf ^ 1, t + 1);
        const short* Qtb = &Qt[buf][0];
#pragma unroll
        for (int sj = 0; sj < 4; ++sj) {
            int ss = 4 * h + sj;
            int q32 = t * 256 + ss * 32;
            if (q32 + 31 < kw) continue;            // fully above diagonal
            bf16x8 qfa = zz, qfb = zz;
            if (g < 2) {
                qfa = *(const bf16x8*)(Qtb + (ss * 32 + c) * 16 + g * 8);
                qfb = *(const bf16x8*)(Qtb + (ss * 32 + 16 + c) * 16 + g * 8);
            }
            f32x4 sA1 = MFMA16(qfa, kfA, z);
            f32x4 sB1 = MFMA16(qfa, kfB, z);
            f32x4 sA2 = MFMA16(qfb, kfA, z);
            f32x4 sB2 = MFMA16(qfb, kfB, z);
            if (q32 >= kw + 32) {                   // fully below diagonal
#pragma unroll
                for (int r = 0; r < 4; ++r) {
                    csA += exp2_fast(sA1[r]) + exp2_fast(sA2[r]);
                    csB += exp2_fast(sB1[r]) + exp2_fast(sB2[r]);
                }
            } else {                                // diagonal region: mask
                int kA = kw + c, kB = kw + 16 + c;
#pragma unroll
                for (int r = 0; r < 4; ++r) {
                    int qa = q32 + 4 * g + r, qb = q32 + 16 + 4 * g + r;
                    csA += (qa >= kA) ? exp2_fast(sA1[r]) : 0.f;
                    csA += (qb >= kA) ? exp2_fast(sA2[r]) : 0.f;
                    csB += (qa >= kB) ? exp2_fast(sB1[r]) : 0.f;
                    csB += (qb >= kB) ? exp2_fast(sB2[r]) : 0.f;
                }
            }
        }
        __syncthreads();
    }
#undef QSTAGE

    csA += __shfl_xor(csA, 16);
    csA += __shfl_xor(csA, 32);
    csB += __shfl_xor(csB, 16);
    csB += __shfl_xor(csB, 32);
    if (lane < 32) csLds[wave][lane] = (lane < 16) ? csA : csB;
    __syncthreads();
    if (tid < 64) {                         // strip = tid>>5, col-in-strip = tid&31
        int st = tid >> 5, col = tid & 31;
        invl[tid] = 1.0f / (csLds[st][col] + csLds[st + 2][col]);
    }
    __syncthreads();
    if (tid < 128) {                        // scale V cols [kc*64, +64)
        int e = tid >> 3, kcol = (tid & 7) * 8;
        size_t vo = (size_t)(hb * 16 + e) * T_SEQ + kc * 64 + kcol;
        bf16x8 v = *(bf16x8*)(Vs + vo);
        bf16x8 o;
#pragma unroll
        for (int j = 0; j < 8; ++j) o[j] = f2bf(bf2f(v[j]) * invl[kcol + j]);
        *(bf16x8*)(Vs + vo) = o;
    }
}

// ---------------------------------------------------------------------------
// K3: attention output. 256-thr blocks (4 waves), grid 1024 (4 blocks/CU),
// quad_rank balanced. rank: qn = 31-(rank>>5) (rank 0 = longest), hb = rank&31.
// Block owns a 64-q chunk; wave w = (strip s=w&1 -> q0w = qn*64+s*32, half
// h=w>>1 -> k-slots {4h..4h+3} of each staged 256-k tile). K linear + V
// e-major XOR-swizzled tiles double-buffered via global_load_lds. Partial O
// combined via LDS. O[q] = sum_{k<=q} exp2(S') * Vs (V pre-scaled).
// ---------------------------------------------------------------------------
__global__ __launch_bounds__(256, 4) void k_attn(const short* __restrict__ Qh,
                                                 const short* __restrict__ Kh,
                                                 const short* __restrict__ Vs,
                                                 short* __restrict__ AObf) {
    __shared__ __align__(16) short Kt[2][4096];
    __shared__ __align__(16) short Vt[2][4096];
    const bf16x8 zz = {0, 0, 0, 0, 0, 0, 0, 0};
    const f32x4 z = {0.f, 0.f, 0.f, 0.f};

    int rank = quad_rank((int)blockIdx.x);
    int qn = 31 - (rank >> 5), hb = rank & 31;
    int h2 = hb >> 2, b = hb & 3;
    int tid = threadIdx.x;
    int wave = tid >> 6, lane = tid & 63;
    int g = lane >> 4, c = lane & 15;
    int s = wave & 1, h = wave >> 1;
    int q0w = qn * 64 + s * 32;
    const size_t hbT = (size_t)hb * T_SEQ;
    const short* Kg = Kh + hbT * 16;
    const short* Vg = Vs + (size_t)hb * 16 * T_SEQ;

    bf16x8 qf0 = zz, qf1 = zz;
    if (g < 2) {
        qf0 = *(const bf16x8*)(Qh + (hbT + q0w + c) * 16 + 8 * g);
        qf1 = *(const bf16x8*)(Qh + (hbT + q0w + 16 + c) * 16 + 8 * g);
    }

    int nT = (qn >> 2) + 1;                 // 256-k tiles this block touches

#define STAGE(bf, kt)                                                        \
    do {                                                                     \
        int k0s = (kt) * 256;                                                \
        gload16(Kg + (size_t)k0s * 16 + tid * 8, &Kt[bf][tid * 8]);          \
        gload16(Kg + (size_t)k0s * 16 + 2048 + tid * 8,                      \
                &Kt[bf][2048 + tid * 8]);                                    \
        int e0 = tid >> 5, j0 = (tid & 31) ^ (e0 & 7);                       \
        gload16(Vg + (size_t)e0 * T_SEQ + k0s + j0 * 8, &Vt[bf][tid * 8]);   \
        int s1_ = tid + 256;                                                 \
        int e1 = s1_ >> 5, j1 = (s1_ & 31) ^ (e1 & 7);                       \
        gload16(Vg + (size_t)e1 * T_SEQ + k0s + j1 * 8,                      \
                &Vt[bf][2048 + tid * 8]);                                    \
    } while (0)

    STAGE(0, 0);
    __syncthreads();

    f32x4 acc0 = z, acc1 = z;
    for (int t = 0; t < nT; ++t) {
        int buf = t & 1;
        if (t + 1 < nT) STAGE(buf ^ 1, t + 1);
        const short* Ktb = &Kt[buf][0];
        const short* Vtb = &Vt[buf][0];
#pragma unroll
        for (int sj = 0; sj < 4; ++sj) {
            int ss = 4 * h + sj;
            int k32 = t * 256 + ss * 32;
            if (k32 > q0w + 31) continue;           // above causal range
            bf16x8 kf0 = zz, kf1 = zz;
            if (g < 2) {
                kf0 = *(const bf16x8*)(Ktb + (ss * 32 + c) * 16 + g * 8);
                kf1 = *(const bf16x8*)(Ktb + (ss * 32 + 16 + c) * 16 + g * 8);
            }
            int ja = ss * 4 + (g >> 1);             // granule in 32-granule row
            const short* vrow = Vtb + c * 256 + ((g & 1) << 2);
            bf16x4 v0 = *(const bf16x4*)(vrow + ((ja ^ (c & 7)) << 3));
            bf16x4 v1 = *(const bf16x4*)(vrow + (((ja + 2) ^ (c & 7)) << 3));
            f32x4 s0 = MFMA16(kf0, qf0, z);
            f32x4 s1 = MFMA16(kf1, qf0, z);
            f32x4 s2 = MFMA16(kf0, qf1, z);
            f32x4 s3 = MFMA16(kf1, qf1, z);
            bf16x8 aA, aB, vf;
            if (k32 + 31 <= q0w) {                  // full pair, no masking
#pragma unroll
                for (int r = 0; r < 4; ++r) {
                    aA[r] = bftrunc(exp2_fast(s0[r]));
                    aA[4 + r] = bftrunc(exp2_fast(s1[r]));
                    aB[r] = bftrunc(exp2_fast(s2[r]));
                    aB[4 + r] = bftrunc(exp2_fast(s3[r]));
                    vf[r] = v0[r];
                    vf[4 + r] = v1[r];
                }
            } else {                                // causal boundary: mask
                int qa = q0w + c, qb = q0w + 16 + c;
                int ka = k32 + 4 * g, kb = k32 + 16 + 4 * g;
#pragma unroll
                for (int r = 0; r < 4; ++r) {
                    aA[r] = (ka + r <= qa) ? bftrunc(exp2_fast(s0[r])) : (short)0;
                    aA[4 + r] = (kb + r <= qa) ? bftrunc(exp2_fast(s1[r])) : (short)0;
                    aB[r] = (ka + r <= qb) ? bftrunc(exp2_fast(s2[r])) : (short)0;
                    aB[4 + r] = (kb + r <= qb) ? bftrunc(exp2_fast(s3[r])) : (short)0;
                    vf[r] = v0[r];
                    vf[4 + r] = v1[r];
                }
            }
            acc0 = MFMA16(aA, vf, acc0);
            acc1 = MFMA16(aB, vf, acc1);
        }
        __syncthreads();
    }
#undef STAGE

    // combine halves: h=1 waves dump partials to LDS, h=0 waves add and store.
    float* Of = (float*)&Kt[0][0];          // 4 KB needed, staging done
    if (h == 1) {
#pragma unroll
        for (int r = 0; r < 4; ++r) {
            Of[r * 128 + s * 64 + lane] = acc0[r];
            Of[(4 + r) * 128 + s * 64 + lane] = acc1[r];
        }
    }
    __syncthreads();
    if (h == 0) {
#pragma unroll
        for (int r = 0; r < 4; ++r) {
            acc0[r] += Of[r * 128 + s * 64 + lane];
            acc1[r] += Of[(4 + r) * 128 + s * 64 + lane];
        }
#pragma unroll
        for (int r = 0; r < 4; ++r) {
            AObf[(size_t)(b * T_SEQ + q0w + 4 * g + r) * DMODEL + h2 * EHEAD + c] = f2bf(acc0[r]);
            AObf[(size_t)(b * T_SEQ + q0w + 16 + 4 * g + r) * DMODEL + h2 * EHEAD + c] = f2bf(acc1[r]);
        }
    }
}

// ---------------------------------------------------------------------------
// K4: fused FF: out = relu(AO@W1+b1)@W2 + b2 + xpe.
// Grid 256 blocks x 256 thr; block owns 32 rows (2 chunks of 16), weights
// loaded into registers ONCE and reused across chunks (halves L2 W-traffic).
// Phase 1: wave w computes F cols [w*128,+128) for both chunks -> LDS
// (32 x 516 padded). Phase 2: wave w computes out cols [w*32,+32).
// ---------------------------------------------------------------------------
__global__ __launch_bounds__(256) void k_ff(const short* __restrict__ AObf,
                                            const short* __restrict__ W1t,
                                            const float* __restrict__ b1,
                                            const short* __restrict__ W2t,
                                            const float* __restrict__ b2,
                                            const float* __restrict__ xpe,
                                            float* __restrict__ out) {
    __shared__ __align__(16) short Fl[32][516];
    int w = threadIdx.x >> 6, lane = threadIdx.x & 63;
    int g = lane >> 4, c = lane & 15;
    int row0 = blockIdx.x * 32;

    // ---- phase 1: F[r][w*128 + n] = relu(AO @ W1 + b1), 2 chunks ----
    {
        bf16x8 wf[8][4];
#pragma unroll
        for (int nt = 0; nt < 8; ++nt)
#pragma unroll
            for (int kk = 0; kk < 4; ++kk)
                wf[nt][kk] = *(const bf16x8*)(W1t + (w * 128 + nt * 16 + c) * 128 + kk * 32 + 8 * g);

#pragma unroll
        for (int ch = 0; ch < 2; ++ch) {
            int rbase = row0 + ch * 16;
            bf16x8 af[4];
#pragma unroll
            for (int kk = 0; kk < 4; ++kk)
                af[kk] = *(const bf16x8*)(AObf + (size_t)(rbase + c) * 128 + kk * 32 + 8 * g);

            f32x4 acc[8];
#pragma unroll
            for (int nt = 0; nt < 8; ++nt) acc[nt] = (f32x4){0.f, 0.f, 0.f, 0.f};
#pragma unroll
            for (int kk = 0; kk < 4; ++kk)
#pragma unroll
                for (int nt = 0; nt < 8; ++nt)
                    acc[nt] = MFMA16(af[kk], wf[nt][kk], acc[nt]);

#pragma unroll
            for (int nt = 0; nt < 8; ++nt) {
                int col = w * 128 + nt * 16 + c;
                float bb = b1[col];
#pragma unroll
                for (int r = 0; r < 4; ++r)
                    Fl[ch * 16 + 4 * g + r][col] = f2bf(fmaxf(acc[nt][r] + bb, 0.f));
            }
        }
    }
    __syncthreads();

    // ---- phase 2: out cols [w*32, +32) = F @ W2 + b2 + xpe, 2 chunks ----
    bf16x8 wf2[2][16];
#pragma unroll
    for (int nt = 0; nt < 2; ++nt)
#pragma unroll
        for (int kk = 0; kk < 16; ++kk)
            wf2[nt][kk] = *(const bf16x8*)(W2t + (w * 32 + nt * 16 + c) * 512 + kk * 32 + 8 * g);

#pragma unroll
    for (int ch = 0; ch < 2; ++ch) {
        int rbase = row0 + ch * 16;
        f32x4 acc2[2];
        acc2[0] = (f32x4){0.f, 0.f, 0.f, 0.f};
        acc2[1] = (f32x4){0.f, 0.f, 0.f, 0.f};
#pragma unroll
        for (int kk = 0; kk < 16; ++kk) {
            bf16x8 a = *(const bf16x8*)(&Fl[ch * 16 + c][kk * 32 + 8 * g]);
            acc2[0] = MFMA16(a, wf2[0][kk], acc2[0]);
            acc2[1] = MFMA16(a, wf2[1][kk], acc2[1]);
        }
#pragma unroll
        for (int nt = 0; nt < 2; ++nt) {
            int col = w * 32 + nt * 16 + c;
            float bb = b2[col];
#pragma unroll
            for (int r = 0; r < 4; ++r) {
                size_t o = (size_t)(rbase + 4 * g + r) * DMODEL + col;
                out[o] = acc2[nt][r] + bb + xpe[o];
            }
        }
    }
}

// ---------------------------------------------------------------------------
extern "C" void kernel_launch(void* const* d_in, const int* in_sizes, int n_in,
                              void* d_out, int out_size, void* d_ws, size_t ws_size,
                              hipStream_t stream) {
    const float* x  = (const float*)d_in[0];
    const float* WQ = (const float*)d_in[1];
    const float* WK = (const float*)d_in[2];
    const float* WV = (const float*)d_in[3];
    const float* W1 = (const float*)d_in[4];
    const float* b1 = (const float*)d_in[5];
    const float* W2 = (const float*)d_in[6];
    const float* b2 = (const float*)d_in[7];
    float* out = (float*)d_out;

    const size_t NTD = (size_t)BATCH * T_SEQ * DMODEL;   // 1048576
    float* xpe   = (float*)d_ws;
    short* Qh    = (short*)(xpe + NTD);
    short* Kh    = Qh + NTD;
    short* Vs    = Kh + NTD;
    short* AObf  = Vs + NTD;
    short* W1t   = AObf + NTD;
    short* W2t   = W1t + 65536;

    k_qkv<<<dim3(128, 4), dim3(256), 0, stream>>>(x, WQ, WK, WV, W1, W2,
                                                  xpe, Qh, Kh, Vs, W1t, W2t);

    k_csum<<<dim3(1024), dim3(256), 0, stream>>>(Qh, Kh, Vs);

    k_attn<<<dim3(1024), dim3(256), 0, stream>>>(Qh, Kh, Vs, AObf);

    k_ff<<<dim3(256), dim3(256), 0, stream>>>(AObf, W1t, b1, W2t, b2, xpe, out);
}

// Round 18
// 54.675 us; speedup vs baseline: 1.6220x; 1.0032x over previous
//
#include <hip/hip_runtime.h>
#include <math.h>
#include <stdint.h>

#define T_SEQ 2048
#define BATCH 4
#define DMODEL 128
#define DFF 512
#define NHEAD 8
#define EHEAD 16

#define QSCALE (0.022097086912079608f * 1.4426950408889634f)   // rsqrt(T) * log2(e)

typedef __attribute__((ext_vector_type(8))) short bf16x8;
typedef __attribute__((ext_vector_type(4))) short bf16x4;
typedef __attribute__((ext_vector_type(4))) float f32x4;

__device__ __forceinline__ short f2bf(float f) {            // RNE
    uint32_t u = __float_as_uint(f);
    u = u + 0x7FFF + ((u >> 16) & 1);
    return (short)(u >> 16);
}
__device__ __forceinline__ short bftrunc(float f) {         // truncate (cheap)
    return (short)(__float_as_uint(f) >> 16);
}
__device__ __forceinline__ float bf2f(short s) {
    return __uint_as_float(((uint32_t)(unsigned short)s) << 16);
}
__device__ __forceinline__ float exp2_fast(float x) {       // raw v_exp_f32
#if __has_builtin(__builtin_amdgcn_exp2f)
    return __builtin_amdgcn_exp2f(x);
#else
    float r; asm("v_exp_f32 %0, %1" : "=v"(r) : "v"(x)); return r;
#endif
}

#define MFMA16(A, B, C) __builtin_amdgcn_mfma_f32_16x16x32_bf16(A, B, C, 0, 0, 0)

__device__ __forceinline__ void gload16(const void* g, void* l) {
    __builtin_amdgcn_global_load_lds(
        (const __attribute__((address_space(1))) void*)g,
        (__attribute__((address_space(3))) void*)l, 16, 0, 0);
}

// oct-complementary rank mapping for 2048 blocks, 8 co-resident per CU:
// IDs {c, c+256, ..., c+1792} -> alternating forward/reversed ranks, so the 8
// blocks sharing a CU have constant total triangular work.
__device__ __forceinline__ int oct_rank(int id) {
    int group = id >> 8, pos = id & 255;
    return (group & 1) ? (((group + 1) << 8) - 1 - pos) : ((group << 8) + pos);
}

// ---------------------------------------------------------------------------
// K1: fused prep + QKV projection. Grid (128, 4), block 256.  (r17 verbatim)
// ---------------------------------------------------------------------------
#define WP 136      // padded LDS row stride (shorts): 272 B, 16B-aligned
__global__ __launch_bounds__(256) void k_qkv(const float* __restrict__ x,
                                             const float* __restrict__ WQ,
                                             const float* __restrict__ WK,
                                             const float* __restrict__ WV,
                                             const float* __restrict__ W1,
                                             const float* __restrict__ W2,
                                             float* __restrict__ xpe,
                                             short* __restrict__ Qh,
                                             short* __restrict__ Kh,
                                             short* __restrict__ Vs,
                                             short* __restrict__ W1t,
                                             short* __restrict__ W2t) {
    __shared__ __align__(16) short Wlds[128 * WP];
    int z = blockIdx.y;
    int tid = threadIdx.x;

    if (z == 3) {                           // W1/W2 -> bf16 transposed
        int base = (int)blockIdx.x * 256 + tid;      // 0..32767
#pragma unroll
        for (int i = 0; i < 2; ++i) {
            int o = base + i * 32768;                // W1t: 65536 = n*128+k
            int n = o >> 7, k = o & 127;
            W1t[o] = f2bf(W1[k * 512 + n]);
        }
#pragma unroll
        for (int i = 0; i < 2; ++i) {
            int o = base + i * 32768;                // W2t: 65536 = n*512+k
            int n = o >> 9, k = o & 511;
            W2t[o] = f2bf(W2[k * 128 + n]);
        }
        return;
    }

    int wave = tid >> 6, lane = tid & 63;
    int g = lane >> 4, c = lane & 15;
    int row0 = blockIdx.x * 64 + wave * 16;
    int row = row0 + c;
    int tloc = row & (T_SEQ - 1);

    {
        const float* Wsrc = (z == 0) ? WQ : (z == 1) ? WK : WV;
        int k = tid & 127, n0 = (tid >> 7) * 64;
        const float* src = Wsrc + k * 128 + n0;
#pragma unroll
        for (int j = 0; j < 64; j += 4) {
            float4 wv = *(const float4*)(src + j);
            Wlds[(n0 + j + 0) * WP + k] = f2bf(wv.x);
            Wlds[(n0 + j + 1) * WP + k] = f2bf(wv.y);
            Wlds[(n0 + j + 2) * WP + k] = f2bf(wv.z);
            Wlds[(n0 + j + 3) * WP + k] = f2bf(wv.w);
        }
    }

    bf16x8 af[4];
#pragma unroll
    for (int kk = 0; kk < 4; ++kk) {
        int d0 = kk * 32 + 8 * g;
        const float* xb = x + (size_t)row * 128 + d0;
        float4 xa = *(const float4*)(xb);
        float4 xc = *(const float4*)(xb + 4);
        float vv[8] = {xa.x, xa.y, xa.z, xa.w, xc.x, xc.y, xc.z, xc.w};
#pragma unroll
        for (int p = 0; p < 4; ++p) {
            int d = d0 + 2 * p;
            float dv = __expf(-(float)d * (9.210340371976184f / 128.0f));
            float ang = (float)tloc * dv;
            vv[2 * p] += __sinf(ang);
            vv[2 * p + 1] += __cosf(ang);
        }
        if (z == 0) {
            float* xo = xpe + (size_t)row * 128 + d0;
            *(float4*)(xo) = make_float4(vv[0], vv[1], vv[2], vv[3]);
            *(float4*)(xo + 4) = make_float4(vv[4], vv[5], vv[6], vv[7]);
        }
#pragma unroll
        for (int j = 0; j < 8; ++j) af[kk][j] = f2bf(vv[j]);
    }
    __syncthreads();

    bf16x8 wf[8][4];
#pragma unroll
    for (int nt = 0; nt < 8; ++nt)
#pragma unroll
        for (int kk = 0; kk < 4; ++kk)
            wf[nt][kk] = *(const bf16x8*)(&Wlds[(nt * 16 + c) * WP + kk * 32 + 8 * g]);

    f32x4 acc[8];
#pragma unroll
    for (int nt = 0; nt < 8; ++nt) acc[nt] = (f32x4){0.f, 0.f, 0.f, 0.f};
#pragma unroll
    for (int kk = 0; kk < 4; ++kk)
#pragma unroll
        for (int nt = 0; nt < 8; ++nt)
            acc[nt] = MFMA16(af[kk], wf[nt][kk], acc[nt]);

    int b = row0 >> 11;
    int t0 = (row0 & (T_SEQ - 1)) + 4 * g;
    if (z < 2) {
        short* dst = (z == 0) ? Qh : Kh;
        float sc = (z == 0) ? QSCALE : 1.0f;
#pragma unroll
        for (int nt = 0; nt < 8; ++nt) {
            int hb = nt * 4 + b;
#pragma unroll
            for (int r = 0; r < 4; ++r)
                dst[(size_t)(hb * T_SEQ + t0 + r) * 16 + c] = f2bf(acc[nt][r] * sc);
        }
    } else {
#pragma unroll
        for (int nt = 0; nt < 8; ++nt) {
            int hb = nt * 4 + b;
            bf16x4 v;
#pragma unroll
            for (int r = 0; r < 4; ++r) v[r] = f2bf(acc[nt][r]);
            *(bf16x4*)(Vs + (size_t)(hb * 16 + c) * T_SEQ + t0) = v;
        }
    }
}
#undef WP

// ---------------------------------------------------------------------------
// K2: column softmax denominators + V scaling. 256-thr blocks (4 waves),
// grid 2048 (8 blocks/CU, oct_rank balanced). rank: kc = rank>>5 (32-col
// chunk, 0 = longest), hb = rank&31. ALL waves share the chunk's 32 cols;
// wave w handles q-slots {2w, 2w+1} of each staged 256-q tile. 4-way partial
// combine via LDS; block scales Vs columns [kc*32, +32) at the end.
// ---------------------------------------------------------------------------
__global__ __launch_bounds__(256, 4) void k_csum(const short* __restrict__ Qh,
                                                 const short* __restrict__ Kh,
                                                 short* __restrict__ Vs) {
    __shared__ __align__(16) short Qt[2][4096];
    __shared__ float csLds[4][32];
    __shared__ float invl[32];
    const bf16x8 zz = {0, 0, 0, 0, 0, 0, 0, 0};
    const f32x4 z = {0.f, 0.f, 0.f, 0.f};

    int rank = oct_rank((int)blockIdx.x);
    int kc = rank >> 5, hb = rank & 31;     // kc 0..63
    int tid = threadIdx.x;
    int wave = tid >> 6, lane = tid & 63;
    int g = lane >> 4, c = lane & 15;
    int kw = kc * 32;
    const size_t hbT = (size_t)hb * T_SEQ;
    const short* Qg = Qh + hbT * 16;

    bf16x8 kfA = zz, kfB = zz;
    if (g < 2) {
        kfA = *(const bf16x8*)(Kh + (hbT + kw + c) * 16 + 8 * g);
        kfB = *(const bf16x8*)(Kh + (hbT + kw + 16 + c) * 16 + 8 * g);
    }

#define QSTAGE(bf, tq)                                                       \
    do {                                                                     \
        const short* src = Qg + (size_t)(tq) * 4096;                         \
        gload16(src + tid * 8, &Qt[bf][tid * 8]);                            \
        gload16(src + 2048 + tid * 8, &Qt[bf][2048 + tid * 8]);              \
    } while (0)

    int tstart = kc >> 3;                   // first 256-q tile with q >= kw
    QSTAGE(0, tstart);
    __syncthreads();

    float csA = 0.f, csB = 0.f;
    for (int t = tstart; t < 8; ++t) {
        int buf = (t - tstart) & 1;
        if (t + 1 < 8) QSTAGE(buf ^ 1, t + 1);
        const short* Qtb = &Qt[buf][0];
#pragma unroll
        for (int sj = 0; sj < 2; ++sj) {
            int ss = 2 * wave + sj;
            int q32 = t * 256 + ss * 32;
            if (q32 + 31 < kw) continue;            // fully above diagonal
            bf16x8 qfa = zz, qfb = zz;
            if (g < 2) {
                qfa = *(const bf16x8*)(Qtb + (ss * 32 + c) * 16 + g * 8);
                qfb = *(const bf16x8*)(Qtb + (ss * 32 + 16 + c) * 16 + g * 8);
            }
            f32x4 sA1 = MFMA16(qfa, kfA, z);
            f32x4 sB1 = MFMA16(qfa, kfB, z);
            f32x4 sA2 = MFMA16(qfb, kfA, z);
            f32x4 sB2 = MFMA16(qfb, kfB, z);
            if (q32 >= kw + 32) {                   // fully below diagonal
#pragma unroll
                for (int r = 0; r < 4; ++r) {
                    csA += exp2_fast(sA1[r]) + exp2_fast(sA2[r]);
                    csB += exp2_fast(sB1[r]) + exp2_fast(sB2[r]);
                }
            } else {                                // diagonal region: mask
                int kA = kw + c, kB = kw + 16 + c;
#pragma unroll
                for (int r = 0; r < 4; ++r) {
                    int qa = q32 + 4 * g + r, qb = q32 + 16 + 4 * g + r;
                    csA += (qa >= kA) ? exp2_fast(sA1[r]) : 0.f;
                    csA += (qb >= kA) ? exp2_fast(sA2[r]) : 0.f;
                    csB += (qa >= kB) ? exp2_fast(sB1[r]) : 0.f;
                    csB += (qb >= kB) ? exp2_fast(sB2[r]) : 0.f;
                }
            }
        }
        __syncthreads();
    }
#undef QSTAGE

    csA += __shfl_xor(csA, 16);
    csA += __shfl_xor(csA, 32);
    csB += __shfl_xor(csB, 16);
    csB += __shfl_xor(csB, 32);
    if (lane < 32) csLds[wave][lane] = (lane < 16) ? csA : csB;
    __syncthreads();
    if (tid < 32)
        invl[tid] = 1.0f / (csLds[0][tid] + csLds[1][tid] +
                            csLds[2][tid] + csLds[3][tid]);
    __syncthreads();
    if (tid < 64) {                         // scale V cols [kw, +32)
        int e = tid >> 2, kg = tid & 3;
        size_t vo = (size_t)(hb * 16 + e) * T_SEQ + kw + kg * 8;
        bf16x8 v = *(bf16x8*)(Vs + vo);
        bf16x8 o;
#pragma unroll
        for (int j = 0; j < 8; ++j) o[j] = f2bf(bf2f(v[j]) * invl[kg * 8 + j]);
        *(bf16x8*)(Vs + vo) = o;
    }
}

// ---------------------------------------------------------------------------
// K3: attention output. 256-thr blocks (4 waves), grid 2048 (8 blocks/CU,
// oct_rank balanced). rank: strip = rank>>5 (0 = longest), q0w = (63-strip)*32,
// hb = rank&31. ALL waves share the chunk's 32 q-rows; wave w handles k-slot
// ss = w of each staged 128-k tile (K linear [128][16] + V e-major [16][128]
// XOR-swizzled, 16 KB dbuf -> 8 blocks/CU). 4-way partial-O combine via LDS.
// O[q] = sum_{k<=q} exp2(S') * Vs (V pre-scaled by 1/colsum).
// ---------------------------------------------------------------------------
__global__ __launch_bounds__(256, 4) void k_attn(const short* __restrict__ Qh,
                                                 const short* __restrict__ Kh,
                                                 const short* __restrict__ Vs,
                                                 short* __restrict__ AObf) {
    __shared__ __align__(16) short Kt[2][2048];
    __shared__ __align__(16) short Vt[2][2048];
    const bf16x8 zz = {0, 0, 0, 0, 0, 0, 0, 0};
    const f32x4 z = {0.f, 0.f, 0.f, 0.f};

    int rank = oct_rank((int)blockIdx.x);
    int strip = rank >> 5;                  // 0 = longest
    int q0w = (63 - strip) * 32;
    int hb = rank & 31;
    int h2 = hb >> 2, b = hb & 3;
    int tid = threadIdx.x;
    int wave = tid >> 6, lane = tid & 63;
    int g = lane >> 4, c = lane & 15;
    const size_t hbT = (size_t)hb * T_SEQ;
    const short* Kg = Kh + hbT * 16;
    const short* Vg = Vs + (size_t)hb * 16 * T_SEQ;

    bf16x8 qf0 = zz, qf1 = zz;
    if (g < 2) {
        qf0 = *(const bf16x8*)(Qh + (hbT + q0w + c) * 16 + 8 * g);
        qf1 = *(const bf16x8*)(Qh + (hbT + q0w + 16 + c) * 16 + 8 * g);
    }

    int nT = (q0w >> 7) + 1;                // 128-k tiles this block touches

    // K: 256 thr x 16B = 4 KB linear [128][16]. V: e0 = tid>>4, granule
    // jp = tid&15 <- global granule j = jp ^ (e0&7) (XOR within 8-granule grp).
#define STAGE(bf, kt)                                                        \
    do {                                                                     \
        int k0s = (kt) * 128;                                                \
        gload16(Kg + (size_t)k0s * 16 + tid * 8, &Kt[bf][tid * 8]);          \
        int e0 = tid >> 4, jp = tid & 15, j0 = jp ^ (e0 & 7);                \
        gload16(Vg + (size_t)e0 * T_SEQ + k0s + j0 * 8, &Vt[bf][tid * 8]);   \
    } while (0)

    STAGE(0, 0);
    __syncthreads();

    f32x4 acc0 = z, acc1 = z;
    for (int t = 0; t < nT; ++t) {
        int buf = t & 1;
        if (t + 1 < nT) STAGE(buf ^ 1, t + 1);
        const short* Ktb = &Kt[buf][0];
        const short* Vtb = &Vt[buf][0];
        int ss = wave;                      // this wave's 32-k slot
        int k32 = t * 128 + ss * 32;
        if (k32 <= q0w + 31) {
            bf16x8 kf0 = zz, kf1 = zz;
            if (g < 2) {
                kf0 = *(const bf16x8*)(Ktb + (ss * 32 + c) * 16 + g * 8);
                kf1 = *(const bf16x8*)(Ktb + (ss * 32 + 16 + c) * 16 + g * 8);
            }
            int ja = ss * 4 + (g >> 1);     // granule in 16-granule row
            const short* vrow = Vtb + c * 128 + ((g & 1) << 2);
            bf16x4 v0 = *(const bf16x4*)(vrow + ((ja ^ (c & 7)) << 3));
            bf16x4 v1 = *(const bf16x4*)(vrow + (((ja + 2) ^ (c & 7)) << 3));
            f32x4 s0 = MFMA16(kf0, qf0, z);
            f32x4 s1 = MFMA16(kf1, qf0, z);
            f32x4 s2 = MFMA16(kf0, qf1, z);
            f32x4 s3 = MFMA16(kf1, qf1, z);
            bf16x8 aA, aB, vf;
            if (k32 + 31 <= q0w) {          // full pair, no masking
#pragma unroll
                for (int r = 0; r < 4; ++r) {
                    aA[r] = bftrunc(exp2_fast(s0[r]));
                    aA[4 + r] = bftrunc(exp2_fast(s1[r]));
                    aB[r] = bftrunc(exp2_fast(s2[r]));
                    aB[4 + r] = bftrunc(exp2_fast(s3[r]));
                    vf[r] = v0[r];
                    vf[4 + r] = v1[r];
                }
            } else {                        // causal boundary: mask
                int qa = q0w + c, qb = q0w + 16 + c;
                int ka = k32 + 4 * g, kb = k32 + 16 + 4 * g;
#pragma unroll
                for (int r = 0; r < 4; ++r) {
                    aA[r] = (ka + r <= qa) ? bftrunc(exp2_fast(s0[r])) : (short)0;
                    aA[4 + r] = (kb + r <= qa) ? bftrunc(exp2_fast(s1[r])) : (short)0;
                    aB[r] = (ka + r <= qb) ? bftrunc(exp2_fast(s2[r])) : (short)0;
                    aB[4 + r] = (kb + r <= qb) ? bftrunc(exp2_fast(s3[r])) : (short)0;
                    vf[r] = v0[r];
                    vf[4 + r] = v1[r];
                }
            }
            acc0 = MFMA16(aA, vf, acc0);
            acc1 = MFMA16(aB, vf, acc1);
        }
        __syncthreads();
    }
#undef STAGE

    // 4-way combine: waves 1..3 dump partials to LDS (6 KB, staging done),
    // wave 0 sums and stores.
    float* Of = (float*)&Kt[0][0];
    if (wave > 0) {
#pragma unroll
        for (int r = 0; r < 4; ++r) {
            Of[((wave - 1) * 8 + r) * 64 + lane] = acc0[r];
            Of[((wave - 1) * 8 + 4 + r) * 64 + lane] = acc1[r];
        }
    }
    __syncthreads();
    if (wave == 0) {
#pragma unroll
        for (int r = 0; r < 4; ++r) {
#pragma unroll
            for (int w = 1; w < 4; ++w) {
                acc0[r] += Of[((w - 1) * 8 + r) * 64 + lane];
                acc1[r] += Of[((w - 1) * 8 + 4 + r) * 64 + lane];
            }
        }
#pragma unroll
        for (int r = 0; r < 4; ++r) {
            AObf[(size_t)(b * T_SEQ + q0w + 4 * g + r) * DMODEL + h2 * EHEAD + c] = f2bf(acc0[r]);
            AObf[(size_t)(b * T_SEQ + q0w + 16 + 4 * g + r) * DMODEL + h2 * EHEAD + c] = f2bf(acc1[r]);
        }
    }
}

// ---------------------------------------------------------------------------
// K4: fused FF: out = relu(AO@W1+b1)@W2 + b2 + xpe.  (r17 verbatim)
// ---------------------------------------------------------------------------
__global__ __launch_bounds__(256) void k_ff(const short* __restrict__ AObf,
                                            const short* __restrict__ W1t,
                                            const float* __restrict__ b1,
                                            const short* __restrict__ W2t,
                                            const float* __restrict__ b2,
                                            const float* __restrict__ xpe,
                                            float* __restrict__ out) {
    __shared__ __align__(16) short Fl[32][516];
    int w = threadIdx.x >> 6, lane = threadIdx.x & 63;
    int g = lane >> 4, c = lane & 15;
    int row0 = blockIdx.x * 32;

    {
        bf16x8 wf[8][4];
#pragma unroll
        for (int nt = 0; nt < 8; ++nt)
#pragma unroll
            for (int kk = 0; kk < 4; ++kk)
                wf[nt][kk] = *(const bf16x8*)(W1t + (w * 128 + nt * 16 + c) * 128 + kk * 32 + 8 * g);

#pragma unroll
        for (int ch = 0; ch < 2; ++ch) {
            int rbase = row0 + ch * 16;
            bf16x8 af[4];
#pragma unroll
            for (int kk = 0; kk < 4; ++kk)
                af[kk] = *(const bf16x8*)(AObf + (size_t)(rbase + c) * 128 + kk * 32 + 8 * g);

            f32x4 acc[8];
#pragma unroll
            for (int nt = 0; nt < 8; ++nt) acc[nt] = (f32x4){0.f, 0.f, 0.f, 0.f};
#pragma unroll
            for (int kk = 0; kk < 4; ++kk)
#pragma unroll
                for (int nt = 0; nt < 8; ++nt)
                    acc[nt] = MFMA16(af[kk], wf[nt][kk], acc[nt]);

#pragma unroll
            for (int nt = 0; nt < 8; ++nt) {
                int col = w * 128 + nt * 16 + c;
                float bb = b1[col];
#pragma unroll
                for (int r = 0; r < 4; ++r)
                    Fl[ch * 16 + 4 * g + r][col] = f2bf(fmaxf(acc[nt][r] + bb, 0.f));
            }
        }
    }
    __syncthreads();

    bf16x8 wf2[2][16];
#pragma unroll
    for (int nt = 0; nt < 2; ++nt)
#pragma unroll
        for (int kk = 0; kk < 16; ++kk)
            wf2[nt][kk] = *(const bf16x8*)(W2t + (w * 32 + nt * 16 + c) * 512 + kk * 32 + 8 * g);

#pragma unroll
    for (int ch = 0; ch < 2; ++ch) {
        int rbase = row0 + ch * 16;
        f32x4 acc2[2];
        acc2[0] = (f32x4){0.f, 0.f, 0.f, 0.f};
        acc2[1] = (f32x4){0.f, 0.f, 0.f, 0.f};
#pragma unroll
        for (int kk = 0; kk < 16; ++kk) {
            bf16x8 a = *(const bf16x8*)(&Fl[ch * 16 + c][kk * 32 + 8 * g]);
            acc2[0] = MFMA16(a, wf2[0][kk], acc2[0]);
            acc2[1] = MFMA16(a, wf2[1][kk], acc2[1]);
        }
#pragma unroll
        for (int nt = 0; nt < 2; ++nt) {
            int col = w * 32 + nt * 16 + c;
            float bb = b2[col];
#pragma unroll
            for (int r = 0; r < 4; ++r) {
                size_t o = (size_t)(rbase + 4 * g + r) * DMODEL + col;
                out[o] = acc2[nt][r] + bb + xpe[o];
            }
        }
    }
}

// ---------------------------------------------------------------------------
extern "C" void kernel_launch(void* const* d_in, const int* in_sizes, int n_in,
                              void* d_out, int out_size, void* d_ws, size_t ws_size,
                              hipStream_t stream) {
    const float* x  = (const float*)d_in[0];
    const float* WQ = (const float*)d_in[1];
    const float* WK = (const float*)d_in[2];
    const float* WV = (const float*)d_in[3];
    const float* W1 = (const float*)d_in[4];
    const float* b1 = (const float*)d_in[5];
    const float* W2 = (const float*)d_in[6];
    const float* b2 = (const float*)d_in[7];
    float* out = (float*)d_out;

    const size_t NTD = (size_t)BATCH * T_SEQ * DMODEL;   // 1048576
    float* xpe   = (float*)d_ws;
    short* Qh    = (short*)(xpe + NTD);
    short* Kh    = Qh + NTD;
    short* Vs    = Kh + NTD;
    short* AObf  = Vs + NTD;
    short* W1t   = AObf + NTD;
    short* W2t   = W1t + 65536;

    k_qkv<<<dim3(128, 4), dim3(256), 0, stream>>>(x, WQ, WK, WV, W1, W2,
                                                  xpe, Qh, Kh, Vs, W1t, W2t);

    k_csum<<<dim3(2048), dim3(256), 0, stream>>>(Qh, Kh, Vs);

    k_attn<<<dim3(2048), dim3(256), 0, stream>>>(Qh, Kh, Vs, AObf);

    k_ff<<<dim3(256), dim3(256), 0, stream>>>(AObf, W1t, b1, W2t, b2, xpe, out);
}